// Round 1
// baseline (6039.004 us; speedup 1.0000x reference)
//
#include <hip/hip_runtime.h>
#include <hip/hip_bf16.h>

#define D128 128

// ---------------- degree count ----------------
__global__ void count_deg(const int* __restrict__ src, const int* __restrict__ dst,
                          int* __restrict__ degs, int* __restrict__ degd, int E)
{
    int e = blockIdx.x * 256 + threadIdx.x;
    if (e < E) {
        atomicAdd(&degs[src[e]], 1);
        atomicAdd(&degd[dst[e]], 1);
    }
}

// ---------------- scatter-add aggregation ----------------
// agg[dst] += x[src] * rsqrt(max(deg_out[src],1)); 2 edges per 256-thread block
__global__ void scatter_add(const float* __restrict__ X, const int* __restrict__ degs,
                            const int* __restrict__ src, const int* __restrict__ dst,
                            float* __restrict__ agg, int E)
{
    int t = threadIdx.x;
    int c = t & 127;
    int eo = t >> 7;
    long e = (long)blockIdx.x * 2 + eo;
    if (e >= E) return;
    int s = src[e], d = dst[e];
    float sc = rsqrtf((float)max(degs[s], 1));
    float v = X[(size_t)s * D128 + c] * sc;
    atomicAdd(&agg[(size_t)d * D128 + c], v);
}

// ---------------- fp32 GEMM: V (+)= (agg * deg_in^-1/2) @ W ----------------
// 64 rows x 128 cols per block, 256 threads, micro-tile 4x8, K split in 2 halves.
__global__ __launch_bounds__(256) void gemm128(
    const float* __restrict__ X, const int* __restrict__ degd,
    const float* __restrict__ W, float* __restrict__ V, int M, int accum)
{
    __shared__ float Wl[64 * 128];   // 32 KB  (K half x 128 cols)
    __shared__ float Xl[64 * 68];    // 17.4 KB (64 rows x 64 K-cols, stride 68)
    int t = threadIdx.x;
    int row0 = blockIdx.x * 64;
    int tr = t >> 4, tc = t & 15;
    int r0 = tr * 4, c0 = tc * 8;

    float acc[4][8];
#pragma unroll
    for (int i = 0; i < 4; i++)
#pragma unroll
        for (int j = 0; j < 8; j++) acc[i][j] = 0.f;

    const float4* X4 = (const float4*)X;
    const float4* W4 = (const float4*)W;
    float4* Wl4 = (float4*)Wl;

    for (int kt = 0; kt < 2; kt++) {
        if (kt) __syncthreads();
        // load X half-tile: 64 rows x 64 cols
#pragma unroll
        for (int i = 0; i < 4; i++) {
            int idx = t + 256 * i;
            int r = idx >> 4, c4 = idx & 15;
            int grow = row0 + r;
            float4 xv = make_float4(0.f, 0.f, 0.f, 0.f);
            if (grow < M) {
                xv = X4[(size_t)grow * 32 + kt * 16 + c4];
                float s = rsqrtf((float)max(degd[grow], 1));
                xv.x *= s; xv.y *= s; xv.z *= s; xv.w *= s;
            }
            *(float4*)&Xl[r * 68 + c4 * 4] = xv;
        }
        // load W half: rows [kt*64, kt*64+64) x 128
#pragma unroll
        for (int i = 0; i < 8; i++)
            Wl4[t + 256 * i] = W4[kt * 2048 + t + 256 * i];
        __syncthreads();

        for (int k = 0; k < 64; k += 4) {
            alignas(16) float xr[4][4];
#pragma unroll
            for (int dr = 0; dr < 4; dr++)
                *(float4*)xr[dr] = *(const float4*)&Xl[(r0 + dr) * 68 + k];
#pragma unroll
            for (int kk = 0; kk < 4; kk++) {
                alignas(16) float w[8];
                *(float4*)&w[0] = *(const float4*)&Wl[(k + kk) * 128 + c0];
                *(float4*)&w[4] = *(const float4*)&Wl[(k + kk) * 128 + c0 + 4];
#pragma unroll
                for (int dr = 0; dr < 4; dr++) {
                    float xv = xr[dr][kk];
#pragma unroll
                    for (int j = 0; j < 8; j++)
                        acc[dr][j] = fmaf(xv, w[j], acc[dr][j]);
                }
            }
        }
    }

#pragma unroll
    for (int dr = 0; dr < 4; dr++) {
        int grow = row0 + r0 + dr;
        if (grow >= M) continue;
        float* vp = V + (size_t)grow * D128 + c0;
        if (accum) {
            float4 o0 = *(float4*)vp;
            float4 o1 = *(float4*)(vp + 4);
            o0.x += acc[dr][0]; o0.y += acc[dr][1]; o0.z += acc[dr][2]; o0.w += acc[dr][3];
            o1.x += acc[dr][4]; o1.y += acc[dr][5]; o1.z += acc[dr][6]; o1.w += acc[dr][7];
            *(float4*)vp = o0;
            *(float4*)(vp + 4) = o1;
        } else {
            float4 o0 = make_float4(acc[dr][0], acc[dr][1], acc[dr][2], acc[dr][3]);
            float4 o1 = make_float4(acc[dr][4], acc[dr][5], acc[dr][6], acc[dr][7]);
            *(float4*)vp = o0;
            *(float4*)(vp + 4) = o1;
        }
    }
}

// ---------------- BN stats: column sum / sumsq ----------------
__global__ __launch_bounds__(256) void bn_stats(const float* __restrict__ V, int M,
                                                float* __restrict__ outsums)
{
    __shared__ float red[256];
    int t = threadIdx.x;
    int c = t & 127, half = t >> 7;
    float s = 0.f, sq = 0.f;
    for (int r = blockIdx.x * 2 + half; r < M; r += 2 * gridDim.x) {
        float v = V[(size_t)r * D128 + c];
        s += v; sq += v * v;
    }
    red[t] = s;
    __syncthreads();
    if (half == 0) atomicAdd(&outsums[c], red[c] + red[128 + c]);
    __syncthreads();
    red[t] = sq;
    __syncthreads();
    if (half == 0) atomicAdd(&outsums[128 + c], red[c] + red[128 + c]);
}

struct FinArgs { int Ms[10]; };

__global__ void bn_finalize(const float* __restrict__ raw, float* __restrict__ fin, FinArgs fa)
{
    int tt = blockIdx.x;
    int c = threadIdx.x;
    float m = (float)fa.Ms[tt];
    float s = raw[tt * 256 + c], sq = raw[tt * 256 + 128 + c];
    float mu = s / m;
    float var = fmaxf(sq / m - mu * mu, 0.f);
    fin[tt * 256 + c] = mu;
    fin[tt * 256 + 128 + c] = rsqrtf(var + 1e-5f);
}

// ---------------- attention score: sum over rows of tanh(y@W1+b1)@w2 ----------------
__global__ __launch_bounds__(256) void attn_score(
    const float* __restrict__ V, const float* __restrict__ st,
    const float* __restrict__ gam, const float* __restrict__ bet,
    const float* __restrict__ pa,
    const float* __restrict__ W1, const float* __restrict__ b1,
    const float* __restrict__ w2, float* __restrict__ Sout, int M)
{
    __shared__ float Wl[64 * 128];
    __shared__ float Xl[64 * 68];
    __shared__ float red[16];
    int t = threadIdx.x;
    int row0 = blockIdx.x * 64;
    int tr = t >> 4, tc = t & 15;
    int r0 = tr * 4, c0 = tc * 8;
    float a = *pa;

    float acc[4][8];
#pragma unroll
    for (int i = 0; i < 4; i++)
#pragma unroll
        for (int j = 0; j < 8; j++) acc[i][j] = 0.f;

    const float4* V4 = (const float4*)V;
    const float4* W4 = (const float4*)W1;
    float4* Wl4 = (float4*)Wl;

    for (int kt = 0; kt < 2; kt++) {
        if (kt) __syncthreads();
#pragma unroll
        for (int i = 0; i < 4; i++) {
            int idx = t + 256 * i;
            int r = idx >> 4, c4 = idx & 15;
            int grow = row0 + r;
            int cs = kt * 16 + c4;   // float4 col index into the 128-wide row
            float4 y = make_float4(0.f, 0.f, 0.f, 0.f);
            if (grow < M) {
                float4 v = V4[(size_t)grow * 32 + cs];
                float4 mu = ((const float4*)st)[cs];
                float4 rs = ((const float4*)(st + 128))[cs];
                float4 g = ((const float4*)gam)[cs];
                float4 b = ((const float4*)bet)[cs];
                y.x = g.x * (v.x - mu.x) * rs.x + b.x; y.x = y.x >= 0.f ? y.x : a * y.x;
                y.y = g.y * (v.y - mu.y) * rs.y + b.y; y.y = y.y >= 0.f ? y.y : a * y.y;
                y.z = g.z * (v.z - mu.z) * rs.z + b.z; y.z = y.z >= 0.f ? y.z : a * y.z;
                y.w = g.w * (v.w - mu.w) * rs.w + b.w; y.w = y.w >= 0.f ? y.w : a * y.w;
            }
            *(float4*)&Xl[r * 68 + c4 * 4] = y;
        }
#pragma unroll
        for (int i = 0; i < 8; i++)
            Wl4[t + 256 * i] = W4[kt * 2048 + t + 256 * i];
        __syncthreads();

        for (int k = 0; k < 64; k += 4) {
            alignas(16) float xr[4][4];
#pragma unroll
            for (int dr = 0; dr < 4; dr++)
                *(float4*)xr[dr] = *(const float4*)&Xl[(r0 + dr) * 68 + k];
#pragma unroll
            for (int kk = 0; kk < 4; kk++) {
                alignas(16) float w[8];
                *(float4*)&w[0] = *(const float4*)&Wl[(k + kk) * 128 + c0];
                *(float4*)&w[4] = *(const float4*)&Wl[(k + kk) * 128 + c0 + 4];
#pragma unroll
                for (int dr = 0; dr < 4; dr++) {
                    float xv = xr[dr][kk];
#pragma unroll
                    for (int j = 0; j < 8; j++)
                        acc[dr][j] = fmaf(xv, w[j], acc[dr][j]);
                }
            }
        }
    }

    alignas(16) float b1v[8], w2v[8];
    *(float4*)&b1v[0] = ((const float4*)b1)[tc * 2];
    *(float4*)&b1v[4] = ((const float4*)b1)[tc * 2 + 1];
    *(float4*)&w2v[0] = ((const float4*)w2)[tc * 2];
    *(float4*)&w2v[4] = ((const float4*)w2)[tc * 2 + 1];

    float thr = 0.f;
#pragma unroll
    for (int dr = 0; dr < 4; dr++) {
        float ssum = 0.f;
#pragma unroll
        for (int j = 0; j < 8; j++)
            ssum += tanhf(acc[dr][j] + b1v[j]) * w2v[j];
        if (row0 + r0 + dr < M) thr += ssum;
    }
#pragma unroll
    for (int off = 1; off < 16; off <<= 1)
        thr += __shfl_xor(thr, off);
    if (tc == 0) red[tr] = thr;
    __syncthreads();
    if (t == 0) {
        float s = 0.f;
#pragma unroll
        for (int i = 0; i < 16; i++) s += red[i];
        atomicAdd(Sout, s);
    }
}

// ---------------- final combine: out = beta0*act(Va) + beta1*act(Vb) ----------------
__global__ void combine(const float* __restrict__ Va, const float* __restrict__ sta,
                        const float* __restrict__ ga, const float* __restrict__ ba,
                        const float* __restrict__ paa,
                        const float* __restrict__ Vb, const float* __restrict__ stb,
                        const float* __restrict__ gb, const float* __restrict__ bb,
                        const float* __restrict__ pab,
                        const float* __restrict__ S, float invM,
                        float* __restrict__ out, int M)
{
    size_t idx = (size_t)blockIdx.x * 256 + threadIdx.x;
    if (idx >= (size_t)M * D128) return;
    int c = (int)(idx & 127);
    float s0 = S[0] * invM, s1 = S[1] * invM;
    float mx = fmaxf(s0, s1);
    float e0 = expf(s0 - mx), e1 = expf(s1 - mx);
    float inv = 1.f / (e0 + e1);
    float b0 = e0 * inv, b1w = e1 * inv;
    float va = Va[idx], vb = Vb[idx];
    float aa = *paa, ab = *pab;
    float ya = ga[c] * (va - sta[c]) * sta[128 + c] + ba[c];
    ya = ya >= 0.f ? ya : aa * ya;
    float yb = gb[c] * (vb - stb[c]) * stb[128 + c] + bb[c];
    yb = yb >= 0.f ? yb : ab * yb;
    out[idx] = b0 * ya + b1w * yb;
}

// ---------------- host orchestration ----------------
extern "C" void kernel_launch(void* const* d_in, const int* in_sizes, int n_in,
                              void* d_out, int out_size, void* d_ws, size_t ws_size,
                              hipStream_t stream)
{
    const float* feats[5] = {
        (const float*)d_in[0], (const float*)d_in[1], (const float*)d_in[2],
        (const float*)d_in[3], (const float*)d_in[4]
    };
    const float* W_blocks = (const float*)d_in[25];
    const float* bn_gamma = (const float*)d_in[27];
    const float* bn_beta  = (const float*)d_in[28];
    const float* prelu_a  = (const float*)d_in[29];
    const float* attn_W1  = (const float*)d_in[30];
    const float* attn_b1  = (const float*)d_in[31];
    const float* attn_w2  = (const float*)d_in[32];
    float* out = (float*)d_out;

    // workspace carve (floats)
    float* wsf = (float*)d_ws;
    float* agg = wsf;                        // 10,240,000 floats
    float* wsv = wsf + 10240000;             // 35,840,000 floats
    int*   degs = (int*)(wsf + 46080000);    // 80,000 ints
    int*   degd = degs + 80000;              // 80,000 ints
    float* statsraw = (float*)(degd + 80000);// 2560
    float* statsfin = statsraw + 2560;       // 2560
    float* Ssum = statsfin + 2560;           // 16
    size_t needed = (size_t)(46080000 + 160000 + 2560 + 2560 + 16) * 4;
    if (ws_size < needed) return;

    // tensor table: T0 d0, T1 d1, T2 dis0, T3 dis4, T4 p1, T5 p2, T6 g2, T7 g3, T8 pw3, T9 pw4
    const int Mt[10]  = {40000, 40000, 40000, 40000, 80000, 80000, 80000, 80000, 40000, 40000};
    const int blk[10] = {0, 1, 0, 4, 1, 2, 2, 3, 3, 4};
    const size_t offp[5] = {0, 5120000, 10240000, 20480000, 30720000};
    float* V[10];
    for (int p = 0; p < 5; p++) {
        V[p * 2]     = out + offp[p];   // first of pair lives in d_out (rewritten by combine)
        V[p * 2 + 1] = wsv + offp[p];
    }

    struct GJob { int tid; int widx; int accum; };
    struct RelH { int feat; int srcIn; int ns; int nd; int E; int njob; GJob jobs[2]; };
    const RelH rels[10] = {
        {0,  5, 40000, 40000,  640000, 2, {{0,  0, 0}, {1,  3, 0}}},  // dd
        {0,  7, 40000, 40000,  640000, 1, {{2,  1, 0}, {0,  0, 0}}},  // ddi
        {1,  9, 40000, 40000,  640000, 2, {{2,  2, 1}, {3, 14, 0}}},  // disdis
        {0, 11, 40000, 80000,  640000, 1, {{4,  4, 0}, {0,  0, 0}}},  // dp
        {2, 13, 80000, 80000, 1280000, 2, {{4,  5, 1}, {5,  6, 0}}},  // pp
        {2, 15, 80000, 80000, 1280000, 1, {{6,  7, 0}, {0,  0, 0}}},  // pg
        {3, 17, 80000, 80000, 1280000, 2, {{6,  8, 1}, {7,  9, 0}}},  // gg
        {3, 19, 80000, 40000, 1280000, 1, {{8, 10, 0}, {0,  0, 0}}},  // gpw
        {4, 21, 40000, 40000,  640000, 2, {{8, 11, 1}, {9, 12, 0}}},  // pwpw
        {4, 23, 40000, 40000,  640000, 1, {{3, 13, 1}, {0,  0, 0}}},  // pwdis
    };

    for (int r = 0; r < 10; r++) {
        const RelH& R = rels[r];
        const int* src = (const int*)d_in[R.srcIn];
        const int* dst = (const int*)d_in[R.srcIn + 1];
        hipMemsetAsync(degs, 0, (size_t)R.ns * sizeof(int), stream);
        hipMemsetAsync(degd, 0, (size_t)R.nd * sizeof(int), stream);
        count_deg<<<(R.E + 255) / 256, 256, 0, stream>>>(src, dst, degs, degd, R.E);
        hipMemsetAsync(agg, 0, (size_t)R.nd * D128 * sizeof(float), stream);
        scatter_add<<<(R.E + 1) / 2, 256, 0, stream>>>(feats[R.feat], degs, src, dst, agg, R.E);
        for (int j = 0; j < R.njob; j++) {
            const GJob& G = R.jobs[j];
            gemm128<<<(R.nd + 63) / 64, 256, 0, stream>>>(
                agg, degd, W_blocks + (size_t)G.widx * 16384, V[G.tid], R.nd, G.accum);
        }
    }

    hipMemsetAsync(statsraw, 0, 2560 * sizeof(float), stream);
    hipMemsetAsync(Ssum, 0, 16 * sizeof(float), stream);
    for (int t = 0; t < 10; t++)
        bn_stats<<<512, 256, 0, stream>>>(V[t], Mt[t], statsraw + t * 256);

    FinArgs fa;
    for (int t = 0; t < 10; t++) fa.Ms[t] = Mt[t];
    bn_finalize<<<10, 128, 0, stream>>>(statsraw, statsfin, fa);

    for (int t = 0; t < 10; t++) {
        int p = t / 2, ch = t % 2;
        attn_score<<<(Mt[t] + 63) / 64, 256, 0, stream>>>(
            V[t], statsfin + t * 256,
            bn_gamma + blk[t] * 128, bn_beta + blk[t] * 128, prelu_a + blk[t],
            attn_W1, attn_b1, attn_w2, Ssum + p * 2 + ch, Mt[t]);
    }

    for (int p = 0; p < 5; p++) {
        int ta = p * 2, tb = p * 2 + 1;
        combine<<<(Mt[ta] * D128 + 255) / 256, 256, 0, stream>>>(
            V[ta], statsfin + ta * 256, bn_gamma + blk[ta] * 128, bn_beta + blk[ta] * 128, prelu_a + blk[ta],
            V[tb], statsfin + tb * 256, bn_gamma + blk[tb] * 128, bn_beta + blk[tb] * 128, prelu_a + blk[tb],
            Ssum + p * 2, 1.0f / Mt[ta], out + offp[p], Mt[ta]);
    }
}

// Round 2
// 4551.372 us; speedup vs baseline: 1.3269x; 1.3269x over previous
//
#include <hip/hip_runtime.h>
#include <hip/hip_bf16.h>

#define D128 128

// ---------------- degree count ----------------
__global__ void count_deg(const int* __restrict__ src, const int* __restrict__ dst,
                          int* __restrict__ degs, int* __restrict__ degd, int E)
{
    int e = blockIdx.x * 256 + threadIdx.x;
    if (e < E) {
        atomicAdd(&degs[src[e]], 1);
        atomicAdd(&degd[dst[e]], 1);
    }
}

// ---------------- one-block chunked exclusive scan: offs[0..n] ----------------
__global__ __launch_bounds__(1024) void scan_offsets(const int* __restrict__ cnt,
                                                     int* __restrict__ offs, int n)
{
    __shared__ int part[1024];
    int t = threadIdx.x;
    int chunk = (n + 1023) / 1024;
    int lo = t * chunk;
    int hi = min(lo + chunk, n);
    int s = 0;
    for (int i = lo; i < hi; i++) s += cnt[i];
    part[t] = s;
    __syncthreads();
    for (int off = 1; off < 1024; off <<= 1) {
        int v = (t >= off) ? part[t - off] : 0;
        __syncthreads();
        part[t] += v;
        __syncthreads();
    }
    int run = (t == 0) ? 0 : part[t - 1];
    for (int i = lo; i < hi; i++) { offs[i] = run; run += cnt[i]; }
    if (hi == n && lo < n) offs[n] = run;
    if (n == 0 && t == 0) offs[0] = 0;
}

// ---------------- bucket fill: ebuf[offs[dst]+k] = src ----------------
__global__ void fill_buckets(const int* __restrict__ src, const int* __restrict__ dst,
                             const int* __restrict__ offs, int* __restrict__ cursor,
                             int* __restrict__ ebuf, int E)
{
    int e = blockIdx.x * 256 + threadIdx.x;
    if (e < E) {
        int d = dst[e];
        int p = atomicAdd(&cursor[d], 1);
        ebuf[offs[d] + p] = src[e];
    }
}

// ---------------- CSR gather: agg[d] = sum_e x[src_e]*deg_out[src_e]^-1/2 ----------------
__global__ __launch_bounds__(256) void gather_agg(
    const float* __restrict__ X, const int* __restrict__ degs,
    const int* __restrict__ offs, const int* __restrict__ ebuf,
    float* __restrict__ agg, int nd)
{
    int t = threadIdx.x;
    int c = t & 127;
    int half = t >> 7;
    int d = blockIdx.x * 2 + half;
    if (d >= nd) return;
    int beg = offs[d], end = offs[d + 1];
    float acc0 = 0.f, acc1 = 0.f;
    int i = beg;
    for (; i + 2 <= end; i += 2) {
        int s0 = ebuf[i], s1 = ebuf[i + 1];
        float sc0 = rsqrtf((float)max(degs[s0], 1));
        float sc1 = rsqrtf((float)max(degs[s1], 1));
        acc0 = fmaf(X[(size_t)s0 * D128 + c], sc0, acc0);
        acc1 = fmaf(X[(size_t)s1 * D128 + c], sc1, acc1);
    }
    if (i < end) {
        int s0 = ebuf[i];
        float sc0 = rsqrtf((float)max(degs[s0], 1));
        acc0 = fmaf(X[(size_t)s0 * D128 + c], sc0, acc0);
    }
    agg[(size_t)d * D128 + c] = acc0 + acc1;
}

// ---------------- fp32 GEMM: V (+)= (agg * deg_in^-1/2) @ W ----------------
__global__ __launch_bounds__(256) void gemm128(
    const float* __restrict__ X, const int* __restrict__ degd,
    const float* __restrict__ W, float* __restrict__ V, int M, int accum)
{
    __shared__ float Wl[64 * 128];   // 32 KB  (K half x 128 cols)
    __shared__ float Xl[64 * 68];    // 17.4 KB (64 rows x 64 K-cols, stride 68)
    int t = threadIdx.x;
    int row0 = blockIdx.x * 64;
    int tr = t >> 4, tc = t & 15;
    int r0 = tr * 4, c0 = tc * 8;

    float acc[4][8];
#pragma unroll
    for (int i = 0; i < 4; i++)
#pragma unroll
        for (int j = 0; j < 8; j++) acc[i][j] = 0.f;

    const float4* X4 = (const float4*)X;
    const float4* W4 = (const float4*)W;
    float4* Wl4 = (float4*)Wl;

    for (int kt = 0; kt < 2; kt++) {
        if (kt) __syncthreads();
#pragma unroll
        for (int i = 0; i < 4; i++) {
            int idx = t + 256 * i;
            int r = idx >> 4, c4 = idx & 15;
            int grow = row0 + r;
            float4 xv = make_float4(0.f, 0.f, 0.f, 0.f);
            if (grow < M) {
                xv = X4[(size_t)grow * 32 + kt * 16 + c4];
                float s = rsqrtf((float)max(degd[grow], 1));
                xv.x *= s; xv.y *= s; xv.z *= s; xv.w *= s;
            }
            *(float4*)&Xl[r * 68 + c4 * 4] = xv;
        }
#pragma unroll
        for (int i = 0; i < 8; i++)
            Wl4[t + 256 * i] = W4[kt * 2048 + t + 256 * i];
        __syncthreads();

        for (int k = 0; k < 64; k += 4) {
            alignas(16) float xr[4][4];
#pragma unroll
            for (int dr = 0; dr < 4; dr++)
                *(float4*)xr[dr] = *(const float4*)&Xl[(r0 + dr) * 68 + k];
#pragma unroll
            for (int kk = 0; kk < 4; kk++) {
                alignas(16) float w[8];
                *(float4*)&w[0] = *(const float4*)&Wl[(k + kk) * 128 + c0];
                *(float4*)&w[4] = *(const float4*)&Wl[(k + kk) * 128 + c0 + 4];
#pragma unroll
                for (int dr = 0; dr < 4; dr++) {
                    float xv = xr[dr][kk];
#pragma unroll
                    for (int j = 0; j < 8; j++)
                        acc[dr][j] = fmaf(xv, w[j], acc[dr][j]);
                }
            }
        }
    }

#pragma unroll
    for (int dr = 0; dr < 4; dr++) {
        int grow = row0 + r0 + dr;
        if (grow >= M) continue;
        float* vp = V + (size_t)grow * D128 + c0;
        if (accum) {
            float4 o0 = *(float4*)vp;
            float4 o1 = *(float4*)(vp + 4);
            o0.x += acc[dr][0]; o0.y += acc[dr][1]; o0.z += acc[dr][2]; o0.w += acc[dr][3];
            o1.x += acc[dr][4]; o1.y += acc[dr][5]; o1.z += acc[dr][6]; o1.w += acc[dr][7];
            *(float4*)vp = o0;
            *(float4*)(vp + 4) = o1;
        } else {
            float4 o0 = make_float4(acc[dr][0], acc[dr][1], acc[dr][2], acc[dr][3]);
            float4 o1 = make_float4(acc[dr][4], acc[dr][5], acc[dr][6], acc[dr][7]);
            *(float4*)vp = o0;
            *(float4*)(vp + 4) = o1;
        }
    }
}

// ---------------- BN stats: column sum / sumsq ----------------
__global__ __launch_bounds__(256) void bn_stats(const float* __restrict__ V, int M,
                                                float* __restrict__ outsums)
{
    __shared__ float red[256];
    int t = threadIdx.x;
    int c = t & 127, half = t >> 7;
    float s = 0.f, sq = 0.f;
    for (int r = blockIdx.x * 2 + half; r < M; r += 2 * gridDim.x) {
        float v = V[(size_t)r * D128 + c];
        s += v; sq += v * v;
    }
    red[t] = s;
    __syncthreads();
    if (half == 0) atomicAdd(&outsums[c], red[c] + red[128 + c]);
    __syncthreads();
    red[t] = sq;
    __syncthreads();
    if (half == 0) atomicAdd(&outsums[128 + c], red[c] + red[128 + c]);
}

struct FinArgs { int Ms[10]; };

__global__ void bn_finalize(const float* __restrict__ raw, float* __restrict__ fin, FinArgs fa)
{
    int tt = blockIdx.x;
    int c = threadIdx.x;
    float m = (float)fa.Ms[tt];
    float s = raw[tt * 256 + c], sq = raw[tt * 256 + 128 + c];
    float mu = s / m;
    float var = fmaxf(sq / m - mu * mu, 0.f);
    fin[tt * 256 + c] = mu;
    fin[tt * 256 + 128 + c] = rsqrtf(var + 1e-5f);
}

// ---------------- attention score: sum over rows of tanh(y@W1+b1)@w2 ----------------
__global__ __launch_bounds__(256) void attn_score(
    const float* __restrict__ V, const float* __restrict__ st,
    const float* __restrict__ gam, const float* __restrict__ bet,
    const float* __restrict__ pa,
    const float* __restrict__ W1, const float* __restrict__ b1,
    const float* __restrict__ w2, float* __restrict__ Sout, int M)
{
    __shared__ float Wl[64 * 128];
    __shared__ float Xl[64 * 68];
    __shared__ float red[16];
    int t = threadIdx.x;
    int row0 = blockIdx.x * 64;
    int tr = t >> 4, tc = t & 15;
    int r0 = tr * 4, c0 = tc * 8;
    float a = *pa;

    float acc[4][8];
#pragma unroll
    for (int i = 0; i < 4; i++)
#pragma unroll
        for (int j = 0; j < 8; j++) acc[i][j] = 0.f;

    const float4* V4 = (const float4*)V;
    const float4* W4 = (const float4*)W1;
    float4* Wl4 = (float4*)Wl;

    for (int kt = 0; kt < 2; kt++) {
        if (kt) __syncthreads();
#pragma unroll
        for (int i = 0; i < 4; i++) {
            int idx = t + 256 * i;
            int r = idx >> 4, c4 = idx & 15;
            int grow = row0 + r;
            int cs = kt * 16 + c4;
            float4 y = make_float4(0.f, 0.f, 0.f, 0.f);
            if (grow < M) {
                float4 v = V4[(size_t)grow * 32 + cs];
                float4 mu = ((const float4*)st)[cs];
                float4 rs = ((const float4*)(st + 128))[cs];
                float4 g = ((const float4*)gam)[cs];
                float4 b = ((const float4*)bet)[cs];
                y.x = g.x * (v.x - mu.x) * rs.x + b.x; y.x = y.x >= 0.f ? y.x : a * y.x;
                y.y = g.y * (v.y - mu.y) * rs.y + b.y; y.y = y.y >= 0.f ? y.y : a * y.y;
                y.z = g.z * (v.z - mu.z) * rs.z + b.z; y.z = y.z >= 0.f ? y.z : a * y.z;
                y.w = g.w * (v.w - mu.w) * rs.w + b.w; y.w = y.w >= 0.f ? y.w : a * y.w;
            }
            *(float4*)&Xl[r * 68 + c4 * 4] = y;
        }
#pragma unroll
        for (int i = 0; i < 8; i++)
            Wl4[t + 256 * i] = W4[kt * 2048 + t + 256 * i];
        __syncthreads();

        for (int k = 0; k < 64; k += 4) {
            alignas(16) float xr[4][4];
#pragma unroll
            for (int dr = 0; dr < 4; dr++)
                *(float4*)xr[dr] = *(const float4*)&Xl[(r0 + dr) * 68 + k];
#pragma unroll
            for (int kk = 0; kk < 4; kk++) {
                alignas(16) float w[8];
                *(float4*)&w[0] = *(const float4*)&Wl[(k + kk) * 128 + c0];
                *(float4*)&w[4] = *(const float4*)&Wl[(k + kk) * 128 + c0 + 4];
#pragma unroll
                for (int dr = 0; dr < 4; dr++) {
                    float xv = xr[dr][kk];
#pragma unroll
                    for (int j = 0; j < 8; j++)
                        acc[dr][j] = fmaf(xv, w[j], acc[dr][j]);
                }
            }
        }
    }

    alignas(16) float b1v[8], w2v[8];
    *(float4*)&b1v[0] = ((const float4*)b1)[tc * 2];
    *(float4*)&b1v[4] = ((const float4*)b1)[tc * 2 + 1];
    *(float4*)&w2v[0] = ((const float4*)w2)[tc * 2];
    *(float4*)&w2v[4] = ((const float4*)w2)[tc * 2 + 1];

    float thr = 0.f;
#pragma unroll
    for (int dr = 0; dr < 4; dr++) {
        float ssum = 0.f;
#pragma unroll
        for (int j = 0; j < 8; j++)
            ssum += tanhf(acc[dr][j] + b1v[j]) * w2v[j];
        if (row0 + r0 + dr < M) thr += ssum;
    }
#pragma unroll
    for (int off = 1; off < 16; off <<= 1)
        thr += __shfl_xor(thr, off);
    if (tc == 0) red[tr] = thr;
    __syncthreads();
    if (t == 0) {
        float s = 0.f;
#pragma unroll
        for (int i = 0; i < 16; i++) s += red[i];
        atomicAdd(Sout, s);
    }
}

// ---------------- final combine: out = beta0*act(Va) + beta1*act(Vb) ----------------
__global__ void combine(const float* __restrict__ Va, const float* __restrict__ sta,
                        const float* __restrict__ ga, const float* __restrict__ ba,
                        const float* __restrict__ paa,
                        const float* __restrict__ Vb, const float* __restrict__ stb,
                        const float* __restrict__ gb, const float* __restrict__ bb,
                        const float* __restrict__ pab,
                        const float* __restrict__ S, float invM,
                        float* __restrict__ out, int M)
{
    size_t idx = (size_t)blockIdx.x * 256 + threadIdx.x;
    if (idx >= (size_t)M * D128) return;
    int c = (int)(idx & 127);
    float s0 = S[0] * invM, s1 = S[1] * invM;
    float mx = fmaxf(s0, s1);
    float e0 = expf(s0 - mx), e1 = expf(s1 - mx);
    float inv = 1.f / (e0 + e1);
    float b0 = e0 * inv, b1w = e1 * inv;
    float va = Va[idx], vb = Vb[idx];
    float aa = *paa, ab = *pab;
    float ya = ga[c] * (va - sta[c]) * sta[128 + c] + ba[c];
    ya = ya >= 0.f ? ya : aa * ya;
    float yb = gb[c] * (vb - stb[c]) * stb[128 + c] + bb[c];
    yb = yb >= 0.f ? yb : ab * yb;
    out[idx] = b0 * ya + b1w * yb;
}

// ---------------- host orchestration ----------------
extern "C" void kernel_launch(void* const* d_in, const int* in_sizes, int n_in,
                              void* d_out, int out_size, void* d_ws, size_t ws_size,
                              hipStream_t stream)
{
    const float* feats[5] = {
        (const float*)d_in[0], (const float*)d_in[1], (const float*)d_in[2],
        (const float*)d_in[3], (const float*)d_in[4]
    };
    const float* W_blocks = (const float*)d_in[25];
    const float* bn_gamma = (const float*)d_in[27];
    const float* bn_beta  = (const float*)d_in[28];
    const float* prelu_a  = (const float*)d_in[29];
    const float* attn_W1  = (const float*)d_in[30];
    const float* attn_b1  = (const float*)d_in[31];
    const float* attn_w2  = (const float*)d_in[32];
    float* out = (float*)d_out;

    // workspace carve (floats/ints)
    float* wsf = (float*)d_ws;
    float* agg = wsf;                        // 10,240,000 floats
    float* wsv = wsf + 10240000;             // 35,840,000 floats
    int*   degs = (int*)(wsf + 46080000);    // 80,000 ints
    int*   degd = degs + 80000;              // 80,000 ints
    float* statsraw = (float*)(degd + 80000);// 2560
    float* statsfin = statsraw + 2560;       // 2560
    float* Ssum = statsfin + 2560;           // 16
    int*   offs   = (int*)(Ssum + 16);       // 80,001 ints
    int*   cursor = offs + 80001;            // 80,000 ints
    int*   ebuf   = cursor + 80000;          // 1,280,000 ints
    size_t needed = (size_t)(46080000 + 160000 + 2560 + 2560 + 16
                             + 80001 + 80000 + 1280000) * 4;
    if (ws_size < needed) return;

    // tensor table: T0 d0, T1 d1, T2 dis0, T3 dis4, T4 p1, T5 p2, T6 g2, T7 g3, T8 pw3, T9 pw4
    const int Mt[10]  = {40000, 40000, 40000, 40000, 80000, 80000, 80000, 80000, 40000, 40000};
    const int blk[10] = {0, 1, 0, 4, 1, 2, 2, 3, 3, 4};
    const size_t offp[5] = {0, 5120000, 10240000, 20480000, 30720000};
    float* V[10];
    for (int p = 0; p < 5; p++) {
        V[p * 2]     = out + offp[p];   // first of pair lives in d_out (rewritten by combine)
        V[p * 2 + 1] = wsv + offp[p];
    }

    struct GJob { int tid; int widx; int accum; };
    struct RelH { int feat; int srcIn; int ns; int nd; int E; int njob; GJob jobs[2]; };
    const RelH rels[10] = {
        {0,  5, 40000, 40000,  640000, 2, {{0,  0, 0}, {1,  3, 0}}},  // dd
        {0,  7, 40000, 40000,  640000, 1, {{2,  1, 0}, {0,  0, 0}}},  // ddi
        {1,  9, 40000, 40000,  640000, 2, {{2,  2, 1}, {3, 14, 0}}},  // disdis
        {0, 11, 40000, 80000,  640000, 1, {{4,  4, 0}, {0,  0, 0}}},  // dp
        {2, 13, 80000, 80000, 1280000, 2, {{4,  5, 1}, {5,  6, 0}}},  // pp
        {2, 15, 80000, 80000, 1280000, 1, {{6,  7, 0}, {0,  0, 0}}},  // pg
        {3, 17, 80000, 80000, 1280000, 2, {{6,  8, 1}, {7,  9, 0}}},  // gg
        {3, 19, 80000, 40000, 1280000, 1, {{8, 10, 0}, {0,  0, 0}}},  // gpw
        {4, 21, 40000, 40000,  640000, 2, {{8, 11, 1}, {9, 12, 0}}},  // pwpw
        {4, 23, 40000, 40000,  640000, 1, {{3, 13, 1}, {0,  0, 0}}},  // pwdis
    };

    for (int r = 0; r < 10; r++) {
        const RelH& R = rels[r];
        const int* src = (const int*)d_in[R.srcIn];
        const int* dst = (const int*)d_in[R.srcIn + 1];
        hipMemsetAsync(degs, 0, (size_t)R.ns * sizeof(int), stream);
        hipMemsetAsync(degd, 0, (size_t)R.nd * sizeof(int), stream);
        hipMemsetAsync(cursor, 0, (size_t)R.nd * sizeof(int), stream);
        count_deg<<<(R.E + 255) / 256, 256, 0, stream>>>(src, dst, degs, degd, R.E);
        scan_offsets<<<1, 1024, 0, stream>>>(degd, offs, R.nd);
        fill_buckets<<<(R.E + 255) / 256, 256, 0, stream>>>(src, dst, offs, cursor, ebuf, R.E);
        gather_agg<<<(R.nd + 1) / 2, 256, 0, stream>>>(
            feats[R.feat], degs, offs, ebuf, agg, R.nd);
        for (int j = 0; j < R.njob; j++) {
            const GJob& G = R.jobs[j];
            gemm128<<<(R.nd + 63) / 64, 256, 0, stream>>>(
                agg, degd, W_blocks + (size_t)G.widx * 16384, V[G.tid], R.nd, G.accum);
        }
    }

    hipMemsetAsync(statsraw, 0, 2560 * sizeof(float), stream);
    hipMemsetAsync(Ssum, 0, 16 * sizeof(float), stream);
    for (int t = 0; t < 10; t++)
        bn_stats<<<512, 256, 0, stream>>>(V[t], Mt[t], statsraw + t * 256);

    FinArgs fa;
    for (int t = 0; t < 10; t++) fa.Ms[t] = Mt[t];
    bn_finalize<<<10, 128, 0, stream>>>(statsraw, statsfin, fa);

    for (int t = 0; t < 10; t++) {
        int p = t / 2, ch = t % 2;
        attn_score<<<(Mt[t] + 63) / 64, 256, 0, stream>>>(
            V[t], statsfin + t * 256,
            bn_gamma + blk[t] * 128, bn_beta + blk[t] * 128, prelu_a + blk[t],
            attn_W1, attn_b1, attn_w2, Ssum + p * 2 + ch, Mt[t]);
    }

    for (int p = 0; p < 5; p++) {
        int ta = p * 2, tb = p * 2 + 1;
        combine<<<(Mt[ta] * D128 + 255) / 256, 256, 0, stream>>>(
            V[ta], statsfin + ta * 256, bn_gamma + blk[ta] * 128, bn_beta + blk[ta] * 128, prelu_a + blk[ta],
            V[tb], statsfin + tb * 256, bn_gamma + blk[tb] * 128, bn_beta + blk[tb] * 128, prelu_a + blk[tb],
            Ssum + p * 2, 1.0f / Mt[ta], out + offp[p], Mt[ta]);
    }
}

// Round 3
// 3816.969 us; speedup vs baseline: 1.5821x; 1.1924x over previous
//
#include <hip/hip_runtime.h>
#include <hip/hip_bf16.h>

#define D128 128

typedef __attribute__((ext_vector_type(8))) short bf16x8;
typedef __attribute__((ext_vector_type(4))) float f32x4;

__device__ inline unsigned short f2bf(float f) {
    unsigned u = __float_as_uint(f);
    u = u + 0x7fffu + ((u >> 16) & 1u);
    return (unsigned short)(u >> 16);
}
__device__ inline float bf2f(unsigned short h) {
    return __uint_as_float(((unsigned)h) << 16);
}

// ---------------- fp32 -> packed bf16 feature conversion ----------------
__global__ __launch_bounds__(256) void xconv(const float* __restrict__ in,
                                             unsigned* __restrict__ out, int n_u)
{
    int i = blockIdx.x * 256 + threadIdx.x;   // handles 4 uints = 8 floats
    if (i * 4 >= n_u) return;
    const float4* in4 = (const float4*)(in + (size_t)i * 8);
    float4 a = in4[0], b = in4[1];
    uint4 o;
    o.x = (unsigned)f2bf(a.x) | ((unsigned)f2bf(a.y) << 16);
    o.y = (unsigned)f2bf(a.z) | ((unsigned)f2bf(a.w) << 16);
    o.z = (unsigned)f2bf(b.x) | ((unsigned)f2bf(b.y) << 16);
    o.w = (unsigned)f2bf(b.z) | ((unsigned)f2bf(b.w) << 16);
    ((uint4*)out)[i] = o;
}

// ---------------- weight transpose + convert: Wt[n][k] = W[k][n] ----------------
__global__ void wconv_t(const float* __restrict__ W_blocks, const float* __restrict__ W1,
                        unsigned short* __restrict__ wt)
{
    int m = blockIdx.x;  // 0..15
    const float* src = (m < 15) ? (W_blocks + (size_t)m * 16384) : W1;
    unsigned short* dst = wt + (size_t)m * 16384;
    for (int i = threadIdx.x; i < 16384; i += 256) {
        int n = i >> 7, k = i & 127;
        dst[i] = f2bf(src[k * 128 + n]);
    }
}

// ---------------- degree count ----------------
__global__ void count_deg(const int* __restrict__ src, const int* __restrict__ dst,
                          int* __restrict__ degs, int* __restrict__ degd, int E)
{
    int e = blockIdx.x * 256 + threadIdx.x;
    if (e < E) {
        atomicAdd(&degs[src[e]], 1);
        atomicAdd(&degd[dst[e]], 1);
    }
}

// ---------------- one-block chunked exclusive scan ----------------
__global__ __launch_bounds__(1024) void scan_offsets(const int* __restrict__ cnt,
                                                     int* __restrict__ offs, int n)
{
    __shared__ int part[1024];
    int t = threadIdx.x;
    int chunk = (n + 1023) / 1024;
    int lo = t * chunk;
    int hi = min(lo + chunk, n);
    int s = 0;
    for (int i = lo; i < hi; i++) s += cnt[i];
    part[t] = s;
    __syncthreads();
    for (int off = 1; off < 1024; off <<= 1) {
        int v = (t >= off) ? part[t - off] : 0;
        __syncthreads();
        part[t] += v;
        __syncthreads();
    }
    int run = (t == 0) ? 0 : part[t - 1];
    for (int i = lo; i < hi; i++) { offs[i] = run; run += cnt[i]; }
    if (hi == n && lo < n) offs[n] = run;
}

// ---------------- bucket fill ----------------
__global__ void fill_buckets(const int* __restrict__ src, const int* __restrict__ dst,
                             const int* __restrict__ offs, int* __restrict__ cursor,
                             int* __restrict__ ebuf, int E)
{
    int e = blockIdx.x * 256 + threadIdx.x;
    if (e < E) {
        int d = dst[e];
        int p = atomicAdd(&cursor[d], 1);
        ebuf[offs[d] + p] = src[e];
    }
}

// ---------------- bf16 CSR gather; deg_in^-1/2 folded; bf16 out ----------------
__global__ __launch_bounds__(256) void gather_bf16(
    const unsigned* __restrict__ Xb, const int* __restrict__ degs,
    const int* __restrict__ degd,
    const int* __restrict__ offs, const int* __restrict__ ebuf,
    unsigned* __restrict__ aggb, int nd)
{
    int t = threadIdx.x;
    int lane = t & 63, r = t >> 6;
    int d = blockIdx.x * 4 + r;
    if (d >= nd) return;
    int beg = offs[d], end = offs[d + 1];
    float a0 = 0.f, a1 = 0.f;
    int i = beg;
    for (; i + 2 <= end; i += 2) {
        int s0 = ebuf[i], s1 = ebuf[i + 1];
        float c0 = rsqrtf((float)max(degs[s0], 1));
        float c1 = rsqrtf((float)max(degs[s1], 1));
        unsigned x0 = Xb[(size_t)s0 * 64 + lane];
        unsigned x1 = Xb[(size_t)s1 * 64 + lane];
        a0 = fmaf(bf2f((unsigned short)(x0 & 0xffff)), c0, a0);
        a1 = fmaf(bf2f((unsigned short)(x0 >> 16)), c0, a1);
        a0 = fmaf(bf2f((unsigned short)(x1 & 0xffff)), c1, a0);
        a1 = fmaf(bf2f((unsigned short)(x1 >> 16)), c1, a1);
    }
    if (i < end) {
        int s0 = ebuf[i];
        float c0 = rsqrtf((float)max(degs[s0], 1));
        unsigned x0 = Xb[(size_t)s0 * 64 + lane];
        a0 = fmaf(bf2f((unsigned short)(x0 & 0xffff)), c0, a0);
        a1 = fmaf(bf2f((unsigned short)(x0 >> 16)), c0, a1);
    }
    float sc = rsqrtf((float)max(degd[d], 1));
    a0 *= sc; a1 *= sc;
    aggb[(size_t)d * 64 + lane] = (unsigned)f2bf(a0) | ((unsigned)f2bf(a1) << 16);
}

// ---------------- MFMA GEMM: V (+)= A_bf16 @ W; fused BN col-stats ----------------
// 64 rows/block, 4 waves x 16 rows, N=128, K=128 via 4 steps of 16x16x32.
__global__ __launch_bounds__(256) void gemm_mfma(
    const unsigned short* __restrict__ A, const unsigned short* __restrict__ Wt,
    float* __restrict__ V, int M, int accum, int do_stats,
    float* __restrict__ statsraw)
{
    __shared__ float ssum[128], ssq[128];
    int t = threadIdx.x;
    int wave = t >> 6, lane = t & 63;
    int lr = lane & 15, lq = lane >> 4;
    int row0 = blockIdx.x * 64 + wave * 16;

    if (t < 128) { ssum[t] = 0.f; ssq[t] = 0.f; }
    __syncthreads();

    f32x4 acc[8];
#pragma unroll
    for (int n = 0; n < 8; n++) acc[n] = (f32x4)(0.f);

    const unsigned short* arow = A + (size_t)(row0 + lr) * 128 + lq * 8;
#pragma unroll
    for (int kt = 0; kt < 4; kt++) {
        bf16x8 af = *(const bf16x8*)(arow + kt * 32);
#pragma unroll
        for (int n = 0; n < 8; n++) {
            bf16x8 bfr = *(const bf16x8*)(Wt + (size_t)(n * 16 + lr) * 128 + kt * 32 + lq * 8);
            acc[n] = __builtin_amdgcn_mfma_f32_16x16x32_bf16(af, bfr, acc[n], 0, 0, 0);
        }
    }

#pragma unroll
    for (int n = 0; n < 8; n++) {
        int col = n * 16 + lr;
        float s_ = 0.f, q_ = 0.f;
#pragma unroll
        for (int reg = 0; reg < 4; reg++) {
            int row = row0 + lq * 4 + reg;
            float v = acc[n][reg];
            float* vp = &V[(size_t)row * D128 + col];
            if (accum) v += *vp;
            *vp = v;
            s_ += v; q_ += v * v;
        }
        if (do_stats) {
            s_ += __shfl_xor(s_, 16); s_ += __shfl_xor(s_, 32);
            q_ += __shfl_xor(q_, 16); q_ += __shfl_xor(q_, 32);
            if (lq == 0) {
                atomicAdd(&ssum[col], s_);
                atomicAdd(&ssq[col], q_);
            }
        }
    }
    if (do_stats) {
        __syncthreads();
        if (t < 128) atomicAdd(&statsraw[t], ssum[t]);
        else atomicAdd(&statsraw[t], ssq[t - 128]);
    }
}

struct FinArgs { int Ms[10]; };

__global__ void bn_finalize(const float* __restrict__ raw, float* __restrict__ fin, FinArgs fa)
{
    int tt = blockIdx.x;
    int c = threadIdx.x;
    float m = (float)fa.Ms[tt];
    float s = raw[tt * 256 + c], sq = raw[tt * 256 + 128 + c];
    float mu = s / m;
    float var = fmaxf(sq / m - mu * mu, 0.f);
    fin[tt * 256 + c] = mu;
    fin[tt * 256 + 128 + c] = rsqrtf(var + 1e-5f);
}

// ---------------- attention score via MFMA: sum over rows of tanh(BN(V)@W1+b1)@w2 ----
__global__ __launch_bounds__(256) void attn_mfma(
    const float* __restrict__ V, const float* __restrict__ st,
    const float* __restrict__ gam, const float* __restrict__ bet,
    const float* __restrict__ pa,
    const unsigned short* __restrict__ W1t, const float* __restrict__ b1,
    const float* __restrict__ w2, float* __restrict__ Sout, int M)
{
    __shared__ float red[4];
    int t = threadIdx.x;
    int wave = t >> 6, lane = t & 63;
    int lr = lane & 15, lq = lane >> 4;
    int row0 = blockIdx.x * 64 + wave * 16;
    float a = *pa;

    f32x4 acc[8];
#pragma unroll
    for (int n = 0; n < 8; n++) acc[n] = (f32x4)(0.f);

    const float* vrow = V + (size_t)(row0 + lr) * D128;
#pragma unroll
    for (int kt = 0; kt < 4; kt++) {
        int k0 = kt * 32 + lq * 8;
        float4 v0 = *(const float4*)(vrow + k0);
        float4 v1 = *(const float4*)(vrow + k0 + 4);
        float4 mu0 = *(const float4*)(st + k0);
        float4 mu1 = *(const float4*)(st + k0 + 4);
        float4 rs0 = *(const float4*)(st + 128 + k0);
        float4 rs1 = *(const float4*)(st + 128 + k0 + 4);
        float4 g0 = *(const float4*)(gam + k0);
        float4 g1 = *(const float4*)(gam + k0 + 4);
        float4 b0 = *(const float4*)(bet + k0);
        float4 b1v = *(const float4*)(bet + k0 + 4);
        float y[8];
        y[0] = g0.x * (v0.x - mu0.x) * rs0.x + b0.x;
        y[1] = g0.y * (v0.y - mu0.y) * rs0.y + b0.y;
        y[2] = g0.z * (v0.z - mu0.z) * rs0.z + b0.z;
        y[3] = g0.w * (v0.w - mu0.w) * rs0.w + b0.w;
        y[4] = g1.x * (v1.x - mu1.x) * rs1.x + b1v.x;
        y[5] = g1.y * (v1.y - mu1.y) * rs1.y + b1v.y;
        y[6] = g1.z * (v1.z - mu1.z) * rs1.z + b1v.z;
        y[7] = g1.w * (v1.w - mu1.w) * rs1.w + b1v.w;
        bf16x8 af;
#pragma unroll
        for (int j = 0; j < 8; j++) {
            float yy = y[j] >= 0.f ? y[j] : a * y[j];
            af[j] = (short)f2bf(yy);
        }
#pragma unroll
        for (int n = 0; n < 8; n++) {
            bf16x8 bfr = *(const bf16x8*)(W1t + (size_t)(n * 16 + lr) * 128 + k0);
            acc[n] = __builtin_amdgcn_mfma_f32_16x16x32_bf16(af, bfr, acc[n], 0, 0, 0);
        }
    }

    float thr = 0.f;
#pragma unroll
    for (int n = 0; n < 8; n++) {
        int col = n * 16 + lr;
        float bc = b1[col], wc = w2[col];
#pragma unroll
        for (int reg = 0; reg < 4; reg++)
            thr += tanhf(acc[n][reg] + bc) * wc;
    }
#pragma unroll
    for (int off = 1; off < 64; off <<= 1)
        thr += __shfl_xor(thr, off);
    if (lane == 0) red[wave] = thr;
    __syncthreads();
    if (t == 0) atomicAdd(Sout, red[0] + red[1] + red[2] + red[3]);
}

// ---------------- final combine ----------------
__global__ void combine(const float* __restrict__ Va, const float* __restrict__ sta,
                        const float* __restrict__ ga, const float* __restrict__ ba,
                        const float* __restrict__ paa,
                        const float* __restrict__ Vb, const float* __restrict__ stb,
                        const float* __restrict__ gb, const float* __restrict__ bb,
                        const float* __restrict__ pab,
                        const float* __restrict__ S, float invM,
                        float* __restrict__ out, int M)
{
    size_t idx = (size_t)blockIdx.x * 256 + threadIdx.x;
    if (idx >= (size_t)M * D128) return;
    int c = (int)(idx & 127);
    float s0 = S[0] * invM, s1 = S[1] * invM;
    float mx = fmaxf(s0, s1);
    float e0 = expf(s0 - mx), e1 = expf(s1 - mx);
    float inv = 1.f / (e0 + e1);
    float b0 = e0 * inv, b1w = e1 * inv;
    float va = Va[idx], vb = Vb[idx];
    float aa = *paa, ab = *pab;
    float ya = ga[c] * (va - sta[c]) * sta[128 + c] + ba[c];
    ya = ya >= 0.f ? ya : aa * ya;
    float yb = gb[c] * (vb - stb[c]) * stb[128 + c] + bb[c];
    yb = yb >= 0.f ? yb : ab * yb;
    out[idx] = b0 * ya + b1w * yb;
}

// ---------------- host orchestration ----------------
extern "C" void kernel_launch(void* const* d_in, const int* in_sizes, int n_in,
                              void* d_out, int out_size, void* d_ws, size_t ws_size,
                              hipStream_t stream)
{
    const float* feats[5] = {
        (const float*)d_in[0], (const float*)d_in[1], (const float*)d_in[2],
        (const float*)d_in[3], (const float*)d_in[4]
    };
    const int featN[5] = {40000, 40000, 80000, 80000, 40000};
    const float* W_blocks = (const float*)d_in[25];
    const float* bn_gamma = (const float*)d_in[27];
    const float* bn_beta  = (const float*)d_in[28];
    const float* prelu_a  = (const float*)d_in[29];
    const float* attn_W1  = (const float*)d_in[30];
    const float* attn_b1  = (const float*)d_in[31];
    const float* attn_w2  = (const float*)d_in[32];
    float* out = (float*)d_out;

    // workspace carve (4-byte slots)
    float* wsf = (float*)d_ws;
    float*    wsv   = wsf;                            // 35,840,000
    unsigned* xbf   = (unsigned*)(wsf + 35840000);    // 5,120,000 uints
    unsigned* aggb  = (unsigned*)(wsf + 40960000);    // 5,120,000 uints
    unsigned short* wtbf = (unsigned short*)(wsf + 46080000); // 262,144 ushorts (131,072 slots)
    int* degs   = (int*)(wsf + 46211072);             // 80,000
    int* degd   = degs + 80000;                       // 80,000
    int* offs   = degd + 80000;                       // 80,001
    int* cursor = offs + 80001;                       // 80,000
    int* ebuf   = cursor + 80000;                     // 1,280,000
    float* statsraw = (float*)(ebuf + 1280000);       // 2,560
    float* statsfin = statsraw + 2560;                // 2,560
    float* Ssum     = statsfin + 2560;                // 16
    size_t needed = ((size_t)(Ssum + 16 - wsf)) * 4;
    if (ws_size < needed) return;

    // tensor table: T0 d0, T1 d1, T2 dis0, T3 dis4, T4 p1, T5 p2, T6 g2, T7 g3, T8 pw3, T9 pw4
    const int Mt[10]  = {40000, 40000, 40000, 40000, 80000, 80000, 80000, 80000, 40000, 40000};
    const int blk[10] = {0, 1, 0, 4, 1, 2, 2, 3, 3, 4};
    const size_t offp[5] = {0, 5120000, 10240000, 20480000, 30720000};
    float* V[10];
    for (int p = 0; p < 5; p++) {
        V[p * 2]     = out + offp[p];
        V[p * 2 + 1] = wsv + offp[p];
    }

    // one-time conversions & zeroing
    wconv_t<<<16, 256, 0, stream>>>(W_blocks, attn_W1, wtbf);
    hipMemsetAsync(statsraw, 0, 2560 * sizeof(float), stream);
    hipMemsetAsync(Ssum, 0, 16 * sizeof(float), stream);

    struct GJob { int tid; int widx; int accum; int stats; };
    struct RelH { int feat; int srcIn; int ns; int nd; int E; int njob; GJob jobs[2]; };
    // feature-major order; accum jobs verified to follow their writers
    const RelH rels[10] = {
        {0,  5, 40000, 40000,  640000, 2, {{0,  0, 0, 1}, {1,  3, 0, 1}}},  // dd
        {0,  7, 40000, 40000,  640000, 1, {{2,  1, 0, 0}, {0,  0, 0, 0}}},  // ddi
        {0, 11, 40000, 80000,  640000, 1, {{4,  4, 0, 0}, {0,  0, 0, 0}}},  // dp
        {1,  9, 40000, 40000,  640000, 2, {{2,  2, 1, 1}, {3, 14, 0, 0}}},  // disdis
        {2, 13, 80000, 80000, 1280000, 2, {{4,  5, 1, 1}, {5,  6, 0, 1}}},  // pp
        {2, 15, 80000, 80000, 1280000, 1, {{6,  7, 0, 0}, {0,  0, 0, 0}}},  // pg
        {3, 17, 80000, 80000, 1280000, 2, {{6,  8, 1, 1}, {7,  9, 0, 1}}},  // gg
        {3, 19, 80000, 40000, 1280000, 1, {{8, 10, 0, 0}, {0,  0, 0, 0}}},  // gpw
        {4, 21, 40000, 40000,  640000, 2, {{8, 11, 1, 1}, {9, 12, 0, 1}}},  // pwpw
        {4, 23, 40000, 40000,  640000, 1, {{3, 13, 1, 1}, {0,  0, 0, 0}}},  // pwdis
    };

    int lastFeat = -1;
    for (int r = 0; r < 10; r++) {
        const RelH& R = rels[r];
        const int* src = (const int*)d_in[R.srcIn];
        const int* dst = (const int*)d_in[R.srcIn + 1];
        if (R.feat != lastFeat) {
            int n_u = featN[R.feat] * 64;
            xconv<<<(n_u / 4 + 255) / 256, 256, 0, stream>>>(feats[R.feat], xbf, n_u);
            lastFeat = R.feat;
        }
        hipMemsetAsync(degs, 0, (size_t)R.ns * sizeof(int), stream);
        hipMemsetAsync(degd, 0, (size_t)R.nd * sizeof(int), stream);
        hipMemsetAsync(cursor, 0, (size_t)R.nd * sizeof(int), stream);
        count_deg<<<(R.E + 255) / 256, 256, 0, stream>>>(src, dst, degs, degd, R.E);
        scan_offsets<<<1, 1024, 0, stream>>>(degd, offs, R.nd);
        fill_buckets<<<(R.E + 255) / 256, 256, 0, stream>>>(src, dst, offs, cursor, ebuf, R.E);
        gather_bf16<<<R.nd / 4, 256, 0, stream>>>(xbf, degs, degd, offs, ebuf, aggb, R.nd);
        for (int j = 0; j < R.njob; j++) {
            const GJob& G = R.jobs[j];
            gemm_mfma<<<R.nd / 64, 256, 0, stream>>>(
                (const unsigned short*)aggb, wtbf + (size_t)G.widx * 16384,
                V[G.tid], R.nd, G.accum, G.stats, statsraw + (size_t)G.tid * 256);
        }
    }

    FinArgs fa;
    for (int t = 0; t < 10; t++) fa.Ms[t] = Mt[t];
    bn_finalize<<<10, 128, 0, stream>>>(statsraw, statsfin, fa);

    for (int t = 0; t < 10; t++) {
        int p = t / 2, ch = t % 2;
        attn_mfma<<<Mt[t] / 64, 256, 0, stream>>>(
            V[t], statsfin + t * 256,
            bn_gamma + blk[t] * 128, bn_beta + blk[t] * 128, prelu_a + blk[t],
            wtbf + (size_t)15 * 16384, attn_b1, attn_w2, Ssum + p * 2 + ch, Mt[t]);
    }

    for (int p = 0; p < 5; p++) {
        int ta = p * 2, tb = p * 2 + 1;
        combine<<<(Mt[ta] * D128 + 255) / 256, 256, 0, stream>>>(
            V[ta], statsfin + ta * 256, bn_gamma + blk[ta] * 128, bn_beta + blk[ta] * 128, prelu_a + blk[ta],
            V[tb], statsfin + tb * 256, bn_gamma + blk[tb] * 128, bn_beta + blk[tb] * 128, prelu_a + blk[tb],
            Ssum + p * 2, 1.0f / Mt[ta], out + offp[p], Mt[ta]);
    }
}

// Round 5
// 3048.843 us; speedup vs baseline: 1.9808x; 1.2519x over previous
//
#include <hip/hip_runtime.h>
#include <hip/hip_bf16.h>

#define D128 128

typedef __attribute__((ext_vector_type(8))) short bf16x8;
typedef __attribute__((ext_vector_type(4))) float f32x4;

__device__ inline unsigned short f2bf(float f) {
    unsigned u = __float_as_uint(f);
    u = u + 0x7fffu + ((u >> 16) & 1u);
    return (unsigned short)(u >> 16);
}
__device__ inline float bf2f(unsigned short h) {
    return __uint_as_float(((unsigned)h) << 16);
}

// ---------------- fp32 -> packed bf16 feature conversion ----------------
__global__ __launch_bounds__(256) void xconv(const float* __restrict__ in,
                                             unsigned* __restrict__ out, int n_u)
{
    int i = blockIdx.x * 256 + threadIdx.x;   // handles 4 uints = 8 floats
    if (i * 4 >= n_u) return;
    const float4* in4 = (const float4*)(in + (size_t)i * 8);
    float4 a = in4[0], b = in4[1];
    uint4 o;
    o.x = (unsigned)f2bf(a.x) | ((unsigned)f2bf(a.y) << 16);
    o.y = (unsigned)f2bf(a.z) | ((unsigned)f2bf(a.w) << 16);
    o.z = (unsigned)f2bf(b.x) | ((unsigned)f2bf(b.y) << 16);
    o.w = (unsigned)f2bf(b.z) | ((unsigned)f2bf(b.w) << 16);
    ((uint4*)out)[i] = o;
}

// ---------------- weight transpose + convert: Wt[n][k] = W[k][n] ----------------
__global__ void wconv_t(const float* __restrict__ W_blocks, const float* __restrict__ W1,
                        unsigned short* __restrict__ wt)
{
    int m = blockIdx.x;  // 0..15
    const float* src = (m < 15) ? (W_blocks + (size_t)m * 16384) : W1;
    unsigned short* dst = wt + (size_t)m * 16384;
    for (int i = threadIdx.x; i < 16384; i += 256) {
        int n = i >> 7, k = i & 127;
        dst[i] = f2bf(src[k * 128 + n]);
    }
}

// ---------------- degree count ----------------
__global__ void count_deg(const int* __restrict__ src, const int* __restrict__ dst,
                          int* __restrict__ degs, int* __restrict__ degd, int E)
{
    int e = blockIdx.x * 256 + threadIdx.x;
    if (e < E) {
        atomicAdd(&degs[src[e]], 1);
        atomicAdd(&degd[dst[e]], 1);
    }
}

// ---------------- hierarchical scan, pass 1: per-block sums (2048 elems/block) ----
__global__ __launch_bounds__(256) void scan_pass1(const int* __restrict__ cnt,
                                                  int* __restrict__ bsums, int n)
{
    __shared__ int ws_[4];
    int b = blockIdx.x, t = threadIdx.x;
    int base = b * 2048 + t * 8;
    int s = 0;
#pragma unroll
    for (int j = 0; j < 8; j++) {
        int i = base + j;
        if (i < n) s += cnt[i];
    }
#pragma unroll
    for (int off = 1; off < 64; off <<= 1) s += __shfl_xor(s, off);
    if ((t & 63) == 0) ws_[t >> 6] = s;
    __syncthreads();
    if (t == 0) bsums[b] = ws_[0] + ws_[1] + ws_[2] + ws_[3];
}

// ---------------- hierarchical scan, pass 2: exclusive scan + block base -------
__global__ __launch_bounds__(256) void scan_pass2(const int* __restrict__ cnt,
                                                  const int* __restrict__ bsums,
                                                  int* __restrict__ offs, int n)
{
    __shared__ int tsum[256];
    __shared__ int sbase;
    int b = blockIdx.x, t = threadIdx.x;
    int base = b * 2048 + t * 8;
    int loc[8];
    int s = 0;
#pragma unroll
    for (int j = 0; j < 8; j++) {
        int i = base + j;
        loc[j] = s;
        s += (i < n) ? cnt[i] : 0;
    }
    tsum[t] = s;
    __syncthreads();
    for (int off = 1; off < 256; off <<= 1) {
        int v = (t >= off) ? tsum[t - off] : 0;
        __syncthreads();
        tsum[t] += v;
        __syncthreads();
    }
    if (t < 64) {
        int v = 0;
        for (int i = t; i < b; i += 64) v += bsums[i];
#pragma unroll
        for (int off = 1; off < 64; off <<= 1) v += __shfl_xor(v, off);
        if (t == 0) sbase = v;
    }
    __syncthreads();
    int tbase = sbase + (t ? tsum[t - 1] : 0);
#pragma unroll
    for (int j = 0; j < 8; j++) {
        int i = base + j;
        if (i < n) offs[i] = tbase + loc[j];
    }
    if (b == gridDim.x - 1 && t == 255) offs[n] = sbase + tsum[255];
}

// ---------------- bucket fill ----------------
__global__ void fill_buckets(const int* __restrict__ src, const int* __restrict__ dst,
                             const int* __restrict__ offs, int* __restrict__ cursor,
                             int* __restrict__ ebuf, int E)
{
    int e = blockIdx.x * 256 + threadIdx.x;
    if (e < E) {
        int d = dst[e];
        int p = atomicAdd(&cursor[d], 1);
        ebuf[offs[d] + p] = src[e];
    }
}

// ---------------- bf16 CSR gather; deg_in^-1/2 folded; bf16 out ----------------
__global__ __launch_bounds__(256) void gather_bf16(
    const unsigned* __restrict__ Xb, const int* __restrict__ degs,
    const int* __restrict__ degd,
    const int* __restrict__ offs, const int* __restrict__ ebuf,
    unsigned* __restrict__ aggb, int nd)
{
    int t = threadIdx.x;
    int lane = t & 63, r = t >> 6;
    int d = blockIdx.x * 4 + r;
    if (d >= nd) return;
    int beg = offs[d], end = offs[d + 1];
    float a0 = 0.f, a1 = 0.f;
    int i = beg;
    for (; i + 2 <= end; i += 2) {
        int s0 = ebuf[i], s1 = ebuf[i + 1];
        float c0 = rsqrtf((float)max(degs[s0], 1));
        float c1 = rsqrtf((float)max(degs[s1], 1));
        unsigned x0 = Xb[(size_t)s0 * 64 + lane];
        unsigned x1 = Xb[(size_t)s1 * 64 + lane];
        a0 = fmaf(bf2f((unsigned short)(x0 & 0xffff)), c0, a0);
        a1 = fmaf(bf2f((unsigned short)(x0 >> 16)), c0, a1);
        a0 = fmaf(bf2f((unsigned short)(x1 & 0xffff)), c1, a0);
        a1 = fmaf(bf2f((unsigned short)(x1 >> 16)), c1, a1);
    }
    if (i < end) {
        int s0 = ebuf[i];
        float c0 = rsqrtf((float)max(degs[s0], 1));
        unsigned x0 = Xb[(size_t)s0 * 64 + lane];
        a0 = fmaf(bf2f((unsigned short)(x0 & 0xffff)), c0, a0);
        a1 = fmaf(bf2f((unsigned short)(x0 >> 16)), c0, a1);
    }
    float sc = rsqrtf((float)max(degd[d], 1));
    a0 *= sc; a1 *= sc;
    aggb[(size_t)d * 64 + lane] = (unsigned)f2bf(a0) | ((unsigned)f2bf(a1) << 16);
}

// ---------------- MFMA GEMM: V (+)= A_bf16 @ W; fused BN col-stats ----------------
__global__ __launch_bounds__(256) void gemm_mfma(
    const unsigned short* __restrict__ A, const unsigned short* __restrict__ Wt,
    float* __restrict__ V, int M, int accum, int do_stats,
    float* __restrict__ statsraw)
{
    __shared__ float ssum[128], ssq[128];
    int t = threadIdx.x;
    int wave = t >> 6, lane = t & 63;
    int lr = lane & 15, lq = lane >> 4;
    int row0 = blockIdx.x * 64 + wave * 16;

    if (t < 128) { ssum[t] = 0.f; ssq[t] = 0.f; }
    __syncthreads();

    f32x4 acc[8];
#pragma unroll
    for (int n = 0; n < 8; n++) acc[n] = (f32x4)(0.f);

    const unsigned short* arow = A + (size_t)(row0 + lr) * 128 + lq * 8;
#pragma unroll
    for (int kt = 0; kt < 4; kt++) {
        bf16x8 af = *(const bf16x8*)(arow + kt * 32);
#pragma unroll
        for (int n = 0; n < 8; n++) {
            bf16x8 bfr = *(const bf16x8*)(Wt + (size_t)(n * 16 + lr) * 128 + kt * 32 + lq * 8);
            acc[n] = __builtin_amdgcn_mfma_f32_16x16x32_bf16(af, bfr, acc[n], 0, 0, 0);
        }
    }

#pragma unroll
    for (int n = 0; n < 8; n++) {
        int col = n * 16 + lr;
        float s_ = 0.f, q_ = 0.f;
#pragma unroll
        for (int reg = 0; reg < 4; reg++) {
            int row = row0 + lq * 4 + reg;
            float v = acc[n][reg];
            float* vp = &V[(size_t)row * D128 + col];
            if (accum) v += *vp;
            *vp = v;
            s_ += v; q_ += v * v;
        }
        if (do_stats) {
            s_ += __shfl_xor(s_, 16); s_ += __shfl_xor(s_, 32);
            q_ += __shfl_xor(q_, 16); q_ += __shfl_xor(q_, 32);
            if (lq == 0) {
                atomicAdd(&ssum[col], s_);
                atomicAdd(&ssq[col], q_);
            }
        }
    }
    if (do_stats) {
        __syncthreads();
        if (t < 128) atomicAdd(&statsraw[t], ssum[t]);
        else atomicAdd(&statsraw[t], ssq[t - 128]);
    }
}

struct FinArgs { int Ms[10]; };

__global__ void bn_finalize(const float* __restrict__ raw, float* __restrict__ fin, FinArgs fa)
{
    int tt = blockIdx.x;
    int c = threadIdx.x;
    float m = (float)fa.Ms[tt];
    float s = raw[tt * 256 + c], sq = raw[tt * 256 + 128 + c];
    float mu = s / m;
    float var = fmaxf(sq / m - mu * mu, 0.f);
    fin[tt * 256 + c] = mu;
    fin[tt * 256 + 128 + c] = rsqrtf(var + 1e-5f);
}

// ---------------- attention score via MFMA ----------------
__global__ __launch_bounds__(256) void attn_mfma(
    const float* __restrict__ V, const float* __restrict__ st,
    const float* __restrict__ gam, const float* __restrict__ bet,
    const float* __restrict__ pa,
    const unsigned short* __restrict__ W1t, const float* __restrict__ b1,
    const float* __restrict__ w2, float* __restrict__ Sout, int M)
{
    __shared__ float red[4];
    int t = threadIdx.x;
    int wave = t >> 6, lane = t & 63;
    int lr = lane & 15, lq = lane >> 4;
    int row0 = blockIdx.x * 64 + wave * 16;
    float a = *pa;

    f32x4 acc[8];
#pragma unroll
    for (int n = 0; n < 8; n++) acc[n] = (f32x4)(0.f);

    const float* vrow = V + (size_t)(row0 + lr) * D128;
#pragma unroll
    for (int kt = 0; kt < 4; kt++) {
        int k0 = kt * 32 + lq * 8;
        float4 v0 = *(const float4*)(vrow + k0);
        float4 v1 = *(const float4*)(vrow + k0 + 4);
        float4 mu0 = *(const float4*)(st + k0);
        float4 mu1 = *(const float4*)(st + k0 + 4);
        float4 rs0 = *(const float4*)(st + 128 + k0);
        float4 rs1 = *(const float4*)(st + 128 + k0 + 4);
        float4 g0 = *(const float4*)(gam + k0);
        float4 g1 = *(const float4*)(gam + k0 + 4);
        float4 b0 = *(const float4*)(bet + k0);
        float4 b1v = *(const float4*)(bet + k0 + 4);
        float y[8];
        y[0] = g0.x * (v0.x - mu0.x) * rs0.x + b0.x;
        y[1] = g0.y * (v0.y - mu0.y) * rs0.y + b0.y;
        y[2] = g0.z * (v0.z - mu0.z) * rs0.z + b0.z;
        y[3] = g0.w * (v0.w - mu0.w) * rs0.w + b0.w;
        y[4] = g1.x * (v1.x - mu1.x) * rs1.x + b1v.x;
        y[5] = g1.y * (v1.y - mu1.y) * rs1.y + b1v.y;
        y[6] = g1.z * (v1.z - mu1.z) * rs1.z + b1v.z;
        y[7] = g1.w * (v1.w - mu1.w) * rs1.w + b1v.w;
        bf16x8 af;
#pragma unroll
        for (int j = 0; j < 8; j++) {
            float yy = y[j] >= 0.f ? y[j] : a * y[j];
            af[j] = (short)f2bf(yy);
        }
#pragma unroll
        for (int n = 0; n < 8; n++) {
            bf16x8 bfr = *(const bf16x8*)(W1t + (size_t)(n * 16 + lr) * 128 + k0);
            acc[n] = __builtin_amdgcn_mfma_f32_16x16x32_bf16(af, bfr, acc[n], 0, 0, 0);
        }
    }

    float thr = 0.f;
#pragma unroll
    for (int n = 0; n < 8; n++) {
        int col = n * 16 + lr;
        float bc = b1[col], wc = w2[col];
#pragma unroll
        for (int reg = 0; reg < 4; reg++)
            thr += tanhf(acc[n][reg] + bc) * wc;
    }
#pragma unroll
    for (int off = 1; off < 64; off <<= 1)
        thr += __shfl_xor(thr, off);
    if (lane == 0) red[wave] = thr;
    __syncthreads();
    if (t == 0) atomicAdd(Sout, red[0] + red[1] + red[2] + red[3]);
}

// ---------------- final combine ----------------
__global__ void combine(const float* __restrict__ Va, const float* __restrict__ sta,
                        const float* __restrict__ ga, const float* __restrict__ ba,
                        const float* __restrict__ paa,
                        const float* __restrict__ Vb, const float* __restrict__ stb,
                        const float* __restrict__ gb, const float* __restrict__ bb,
                        const float* __restrict__ pab,
                        const float* __restrict__ S, float invM,
                        float* __restrict__ out, int M)
{
    size_t idx = (size_t)blockIdx.x * 256 + threadIdx.x;
    if (idx >= (size_t)M * D128) return;
    int c = (int)(idx & 127);
    float s0 = S[0] * invM, s1 = S[1] * invM;
    float mx = fmaxf(s0, s1);
    float e0 = expf(s0 - mx), e1 = expf(s1 - mx);
    float inv = 1.f / (e0 + e1);
    float b0 = e0 * inv, b1w = e1 * inv;
    float va = Va[idx], vb = Vb[idx];
    float aa = *paa, ab = *pab;
    float ya = ga[c] * (va - sta[c]) * sta[128 + c] + ba[c];
    ya = ya >= 0.f ? ya : aa * ya;
    float yb = gb[c] * (vb - stb[c]) * stb[128 + c] + bb[c];
    yb = yb >= 0.f ? yb : ab * yb;
    out[idx] = b0 * ya + b1w * yb;
}

// ---------------- host orchestration ----------------
extern "C" void kernel_launch(void* const* d_in, const int* in_sizes, int n_in,
                              void* d_out, int out_size, void* d_ws, size_t ws_size,
                              hipStream_t stream)
{
    const float* feats[5] = {
        (const float*)d_in[0], (const float*)d_in[1], (const float*)d_in[2],
        (const float*)d_in[3], (const float*)d_in[4]
    };
    const int featN[5] = {40000, 40000, 80000, 80000, 40000};
    const float* W_blocks = (const float*)d_in[25];
    const float* bn_gamma = (const float*)d_in[27];
    const float* bn_beta  = (const float*)d_in[28];
    const float* prelu_a  = (const float*)d_in[29];
    const float* attn_W1  = (const float*)d_in[30];
    const float* attn_b1  = (const float*)d_in[31];
    const float* attn_w2  = (const float*)d_in[32];
    float* out = (float*)d_out;

    // workspace carve (4-byte slots)
    float* wsf = (float*)d_ws;
    float*    wsv   = wsf;                            // 35,840,000 floats
    unsigned* xbf   = (unsigned*)(wsf + 35840000);    // 5,120,000 uints
    unsigned* aggb  = (unsigned*)(wsf + 40960000);    // 5,120,000 uints
    unsigned short* wtbf = (unsigned short*)(wsf + 46080000); // 262,144 ushorts
    int* degs   = (int*)(wsf + 46211072);             // 80,000 (degs+degd+cursor: one memset)
    int* degd   = degs + 80000;                       // 80,000
    int* cursor = degd + 80000;                       // 80,000
    int* offs   = cursor + 80000;                     // 80,001
    int* bsums  = offs + 80001;                       // 64
    int* ebuf   = bsums + 64;                         // 1,280,000
    float* statsraw = (float*)(ebuf + 1280000);       // 2,560
    float* statsfin = statsraw + 2560;                // 2,560
    float* Ssum     = statsfin + 2560;                // 16
    size_t needed = ((size_t)(Ssum + 16 - wsf)) * 4;
    if (ws_size < needed) return;

    // tensor table: T0 d0, T1 d1, T2 dis0, T3 dis4, T4 p1, T5 p2, T6 g2, T7 g3, T8 pw3, T9 pw4
    const int Mt[10]  = {40000, 40000, 40000, 40000, 80000, 80000, 80000, 80000, 40000, 40000};
    const int blk[10] = {0, 1, 0, 4, 1, 2, 2, 3, 3, 4};
    const size_t offp[5] = {0, 5120000, 10240000, 20480000, 30720000};
    float* V[10];
    for (int p = 0; p < 5; p++) {
        V[p * 2]     = out + offp[p];
        V[p * 2 + 1] = wsv + offp[p];
    }

    wconv_t<<<16, 256, 0, stream>>>(W_blocks, attn_W1, wtbf);
    hipMemsetAsync(statsraw, 0, 2560 * sizeof(float), stream);
    hipMemsetAsync(Ssum, 0, 16 * sizeof(float), stream);

    struct GJob { int tid; int widx; int accum; int stats; };
    struct RelH { int feat; int srcIn; int ns; int nd; int E; int njob; GJob jobs[2]; };
    const RelH rels[10] = {
        {0,  5, 40000, 40000,  640000, 2, {{0,  0, 0, 1}, {1,  3, 0, 1}}},  // dd
        {0,  7, 40000, 40000,  640000, 1, {{2,  1, 0, 0}, {0,  0, 0, 0}}},  // ddi
        {0, 11, 40000, 80000,  640000, 1, {{4,  4, 0, 0}, {0,  0, 0, 0}}},  // dp
        {1,  9, 40000, 40000,  640000, 2, {{2,  2, 1, 1}, {3, 14, 0, 0}}},  // disdis
        {2, 13, 80000, 80000, 1280000, 2, {{4,  5, 1, 1}, {5,  6, 0, 1}}},  // pp
        {2, 15, 80000, 80000, 1280000, 1, {{6,  7, 0, 0}, {0,  0, 0, 0}}},  // pg
        {3, 17, 80000, 80000, 1280000, 2, {{6,  8, 1, 1}, {7,  9, 0, 1}}},  // gg
        {3, 19, 80000, 40000, 1280000, 1, {{8, 10, 0, 0}, {0,  0, 0, 0}}},  // gpw
        {4, 21, 40000, 40000,  640000, 2, {{8, 11, 1, 1}, {9, 12, 0, 1}}},  // pwpw
        {4, 23, 40000, 40000,  640000, 1, {{3, 13, 1, 1}, {0,  0, 0, 0}}},  // pwdis
    };

    int lastFeat = -1;
    for (int r = 0; r < 10; r++) {
        const RelH& R = rels[r];
        const int* src = (const int*)d_in[R.srcIn];
        const int* dst = (const int*)d_in[R.srcIn + 1];
        if (R.feat != lastFeat) {
            int n_u = featN[R.feat] * 64;
            xconv<<<(n_u / 4 + 255) / 256, 256, 0, stream>>>(feats[R.feat], xbf, n_u);
            lastFeat = R.feat;
        }
        hipMemsetAsync(degs, 0, (size_t)240000 * sizeof(int), stream);
        count_deg<<<(R.E + 255) / 256, 256, 0, stream>>>(src, dst, degs, degd, R.E);
        int nb = (R.nd + 2047) / 2048;
        scan_pass1<<<nb, 256, 0, stream>>>(degd, bsums, R.nd);
        scan_pass2<<<nb, 256, 0, stream>>>(degd, bsums, offs, R.nd);
        fill_buckets<<<(R.E + 255) / 256, 256, 0, stream>>>(src, dst, offs, cursor, ebuf, R.E);
        gather_bf16<<<R.nd / 4, 256, 0, stream>>>(xbf, degs, degd, offs, ebuf, aggb, R.nd);
        for (int j = 0; j < R.njob; j++) {
            const GJob& G = R.jobs[j];
            gemm_mfma<<<R.nd / 64, 256, 0, stream>>>(
                (const unsigned short*)aggb, wtbf + (size_t)G.widx * 16384,
                V[G.tid], R.nd, G.accum, G.stats, statsraw + (size_t)G.tid * 256);
        }
    }

    FinArgs fa;
    for (int t = 0; t < 10; t++) fa.Ms[t] = Mt[t];
    bn_finalize<<<10, 128, 0, stream>>>(statsraw, statsfin, fa);

    for (int t = 0; t < 10; t++) {
        int p = t / 2, ch = t % 2;
        attn_mfma<<<Mt[t] / 64, 256, 0, stream>>>(
            V[t], statsfin + t * 256,
            bn_gamma + blk[t] * 128, bn_beta + blk[t] * 128, prelu_a + blk[t],
            wtbf + (size_t)15 * 16384, attn_b1, attn_w2, Ssum + p * 2 + ch, Mt[t]);
    }

    for (int p = 0; p < 5; p++) {
        int ta = p * 2, tb = p * 2 + 1;
        combine<<<(Mt[ta] * D128 + 255) / 256, 256, 0, stream>>>(
            V[ta], statsfin + ta * 256, bn_gamma + blk[ta] * 128, bn_beta + blk[ta] * 128, prelu_a + blk[ta],
            V[tb], statsfin + tb * 256, bn_gamma + blk[tb] * 128, bn_beta + blk[tb] * 128, prelu_a + blk[tb],
            Ssum + p * 2, 1.0f / Mt[ta], out + offp[p], Mt[ta]);
    }
}

// Round 6
// 2477.173 us; speedup vs baseline: 2.4379x; 1.2308x over previous
//
#include <hip/hip_runtime.h>
#include <hip/hip_bf16.h>

#define D128 128
#define CAP 64

typedef __attribute__((ext_vector_type(8))) short bf16x8;
typedef __attribute__((ext_vector_type(4))) float f32x4;

__device__ inline unsigned short f2bf(float f) {
    unsigned u = __float_as_uint(f);
    u = u + 0x7fffu + ((u >> 16) & 1u);
    return (unsigned short)(u >> 16);
}
__device__ inline float bf2f(unsigned short h) {
    return __uint_as_float(((unsigned)h) << 16);
}

// ---------------- fp32 -> packed bf16 feature conversion ----------------
__global__ __launch_bounds__(256) void xconv(const float* __restrict__ in,
                                             unsigned* __restrict__ out, int n_u)
{
    int i = blockIdx.x * 256 + threadIdx.x;   // 4 uints = 8 floats each
    if (i * 4 >= n_u) return;
    const float4* in4 = (const float4*)(in + (size_t)i * 8);
    float4 a = in4[0], b = in4[1];
    uint4 o;
    o.x = (unsigned)f2bf(a.x) | ((unsigned)f2bf(a.y) << 16);
    o.y = (unsigned)f2bf(a.z) | ((unsigned)f2bf(a.w) << 16);
    o.z = (unsigned)f2bf(b.x) | ((unsigned)f2bf(b.y) << 16);
    o.w = (unsigned)f2bf(b.z) | ((unsigned)f2bf(b.w) << 16);
    ((uint4*)out)[i] = o;
}

// ---------------- weight transpose + convert: Wt[n][k] = W[k][n] ----------------
__global__ void wconv_t(const float* __restrict__ W_blocks, const float* __restrict__ W1,
                        unsigned short* __restrict__ wt)
{
    int m = blockIdx.x;  // 0..15
    const float* src = (m < 15) ? (W_blocks + (size_t)m * 16384) : W1;
    unsigned short* dst = wt + (size_t)m * 16384;
    for (int i = threadIdx.x; i < 16384; i += 256) {
        int n = i >> 7, k = i & 127;
        dst[i] = f2bf(src[k * 128 + n]);
    }
}

// ================= PATH A: fused capped-bucket CSR build =================
__global__ __launch_bounds__(256) void fused_fill(
    const int* __restrict__ src, const int* __restrict__ dst,
    int* __restrict__ degs, int* __restrict__ cursor,
    int* __restrict__ ebuf, int* __restrict__ oflow, int E)
{
    int e = blockIdx.x * 256 + threadIdx.x;
    if (e >= E) return;
    int s = src[e], d = dst[e];
    atomicAdd(&degs[s], 1);
    int p = atomicAdd(&cursor[d], 1);
    if (p < CAP) ebuf[d * CAP + p] = s;
    else {
        int q = atomicAdd(&oflow[0], 1);
        if (q < 4095) { oflow[2 + 2 * q] = d; oflow[3 + 2 * q] = s; }
    }
}

// exact fixup for (astronomically unlikely) bucket overflow
__global__ void oflow_fix(const unsigned* __restrict__ Xb, const int* __restrict__ degs,
                          const int* __restrict__ cursor, const int* __restrict__ oflow,
                          unsigned* __restrict__ aggb)
{
    int n = oflow[0]; if (n > 4095) n = 4095;
    int lane = threadIdx.x;  // 64
    for (int i = 0; i < n; i++) {
        int d = oflow[2 + 2 * i], s = oflow[3 + 2 * i];
        float cs = rsqrtf((float)max(degs[s], 1));
        float cd = rsqrtf((float)max(cursor[d], 1));
        unsigned x = Xb[(size_t)s * 64 + lane];
        unsigned a = aggb[(size_t)d * 64 + lane];
        float a0 = bf2f((unsigned short)(a & 0xffff)) + bf2f((unsigned short)(x & 0xffff)) * cs * cd;
        float a1 = bf2f((unsigned short)(a >> 16)) + bf2f((unsigned short)(x >> 16)) * cs * cd;
        aggb[(size_t)d * 64 + lane] = (unsigned)f2bf(a0) | ((unsigned)f2bf(a1) << 16);
    }
}

// ================= PATH B fallback: two-pass CSR build =================
__global__ void count_deg(const int* __restrict__ src, const int* __restrict__ dst,
                          int* __restrict__ degs, int* __restrict__ degd, int E)
{
    int e = blockIdx.x * 256 + threadIdx.x;
    if (e < E) {
        atomicAdd(&degs[src[e]], 1);
        atomicAdd(&degd[dst[e]], 1);
    }
}

__global__ __launch_bounds__(256) void scan_pass1(const int* __restrict__ cnt,
                                                  int* __restrict__ bsums, int n)
{
    __shared__ int ws_[4];
    int b = blockIdx.x, t = threadIdx.x;
    int base = b * 2048 + t * 8;
    int s = 0;
#pragma unroll
    for (int j = 0; j < 8; j++) {
        int i = base + j;
        if (i < n) s += cnt[i];
    }
#pragma unroll
    for (int off = 1; off < 64; off <<= 1) s += __shfl_xor(s, off);
    if ((t & 63) == 0) ws_[t >> 6] = s;
    __syncthreads();
    if (t == 0) bsums[b] = ws_[0] + ws_[1] + ws_[2] + ws_[3];
}

__global__ __launch_bounds__(256) void scan_pass2(const int* __restrict__ cnt,
                                                  const int* __restrict__ bsums,
                                                  int* __restrict__ offs, int n)
{
    __shared__ int tsum[256];
    __shared__ int sbase;
    int b = blockIdx.x, t = threadIdx.x;
    int base = b * 2048 + t * 8;
    int loc[8];
    int s = 0;
#pragma unroll
    for (int j = 0; j < 8; j++) {
        int i = base + j;
        loc[j] = s;
        s += (i < n) ? cnt[i] : 0;
    }
    tsum[t] = s;
    __syncthreads();
    for (int off = 1; off < 256; off <<= 1) {
        int v = (t >= off) ? tsum[t - off] : 0;
        __syncthreads();
        tsum[t] += v;
        __syncthreads();
    }
    if (t < 64) {
        int v = 0;
        for (int i = t; i < b; i += 64) v += bsums[i];
#pragma unroll
        for (int off = 1; off < 64; off <<= 1) v += __shfl_xor(v, off);
        if (t == 0) sbase = v;
    }
    __syncthreads();
    int tbase = sbase + (t ? tsum[t - 1] : 0);
#pragma unroll
    for (int j = 0; j < 8; j++) {
        int i = base + j;
        if (i < n) offs[i] = tbase + loc[j];
    }
    if (b == gridDim.x - 1 && t == 255) offs[n] = sbase + tsum[255];
}

__global__ void fill_buckets(const int* __restrict__ src, const int* __restrict__ dst,
                             const int* __restrict__ offs, int* __restrict__ cursor,
                             int* __restrict__ ebuf, int E)
{
    int e = blockIdx.x * 256 + threadIdx.x;
    if (e < E) {
        int d = dst[e];
        int p = atomicAdd(&cursor[d], 1);
        ebuf[offs[d] + p] = src[e];
    }
}

// ---------------- bf16 CSR gather (both modes); deg_in^-1/2 folded ----------------
__global__ __launch_bounds__(256) void gather_bf16(
    const unsigned* __restrict__ Xb, const int* __restrict__ degs,
    const int* __restrict__ degd,   // path A: cursor
    const int* __restrict__ offs,   // path B only
    const int* __restrict__ ebuf,
    unsigned* __restrict__ aggb, int nd, int capmode)
{
    int t = threadIdx.x;
    int lane = t & 63, r = t >> 6;
    int d = blockIdx.x * 4 + r;
    if (d >= nd) return;
    int beg, end, cnt;
    if (capmode) {
        cnt = degd[d];
        beg = d * CAP;
        end = beg + min(cnt, CAP);
    } else {
        beg = offs[d];
        end = offs[d + 1];
        cnt = end - beg;
    }
    float a0 = 0.f, a1 = 0.f;
    int i = beg;
    for (; i + 2 <= end; i += 2) {
        int s0 = ebuf[i], s1 = ebuf[i + 1];
        float c0 = rsqrtf((float)max(degs[s0], 1));
        float c1 = rsqrtf((float)max(degs[s1], 1));
        unsigned x0 = Xb[(size_t)s0 * 64 + lane];
        unsigned x1 = Xb[(size_t)s1 * 64 + lane];
        a0 = fmaf(bf2f((unsigned short)(x0 & 0xffff)), c0, a0);
        a1 = fmaf(bf2f((unsigned short)(x0 >> 16)), c0, a1);
        a0 = fmaf(bf2f((unsigned short)(x1 & 0xffff)), c1, a0);
        a1 = fmaf(bf2f((unsigned short)(x1 >> 16)), c1, a1);
    }
    if (i < end) {
        int s0 = ebuf[i];
        float c0 = rsqrtf((float)max(degs[s0], 1));
        unsigned x0 = Xb[(size_t)s0 * 64 + lane];
        a0 = fmaf(bf2f((unsigned short)(x0 & 0xffff)), c0, a0);
        a1 = fmaf(bf2f((unsigned short)(x0 >> 16)), c0, a1);
    }
    float sc = rsqrtf((float)max(cnt, 1));
    a0 *= sc; a1 *= sc;
    aggb[(size_t)d * 64 + lane] = (unsigned)f2bf(a0) | ((unsigned)f2bf(a1) << 16);
}

// ---------------- MFMA GEMM epilogue (shared) ----------------
__device__ __forceinline__ void gemm_epi(
    f32x4* acc, float* __restrict__ V, int accum, int do_stats,
    float* ssum, float* ssq, int row0, int lr, int lq)
{
#pragma unroll
    for (int n = 0; n < 8; n++) {
        int col = n * 16 + lr;
        float s_ = 0.f, q_ = 0.f;
#pragma unroll
        for (int reg = 0; reg < 4; reg++) {
            int row = row0 + lq * 4 + reg;
            float v = acc[n][reg];
            float* vp = &V[(size_t)row * D128 + col];
            if (accum) v += *vp;
            *vp = v;
            s_ += v; q_ += v * v;
        }
        if (do_stats) {
            s_ += __shfl_xor(s_, 16); s_ += __shfl_xor(s_, 32);
            q_ += __shfl_xor(q_, 16); q_ += __shfl_xor(q_, 32);
            if (lq == 0) {
                atomicAdd(&ssum[col], s_);
                atomicAdd(&ssq[col], q_);
            }
        }
    }
}

// ---------------- single-output MFMA GEMM ----------------
__global__ __launch_bounds__(256) void gemm_mfma(
    const unsigned short* __restrict__ A, const unsigned short* __restrict__ Wt,
    float* __restrict__ V, int M, int accum, int do_stats,
    float* __restrict__ statsraw)
{
    __shared__ float ssum[128], ssq[128];
    int t = threadIdx.x;
    int wave = t >> 6, lane = t & 63;
    int lr = lane & 15, lq = lane >> 4;
    int row0 = blockIdx.x * 64 + wave * 16;

    if (t < 128) { ssum[t] = 0.f; ssq[t] = 0.f; }
    __syncthreads();

    f32x4 acc[8];
#pragma unroll
    for (int n = 0; n < 8; n++) acc[n] = (f32x4)(0.f);

    const unsigned short* arow = A + (size_t)(row0 + lr) * 128 + lq * 8;
#pragma unroll
    for (int kt = 0; kt < 4; kt++) {
        bf16x8 af = *(const bf16x8*)(arow + kt * 32);
#pragma unroll
        for (int n = 0; n < 8; n++) {
            bf16x8 bfr = *(const bf16x8*)(Wt + (size_t)(n * 16 + lr) * 128 + kt * 32 + lq * 8);
            acc[n] = __builtin_amdgcn_mfma_f32_16x16x32_bf16(af, bfr, acc[n], 0, 0, 0);
        }
    }
    gemm_epi(acc, V, accum, do_stats, ssum, ssq, row0, lr, lq);
    if (do_stats) {
        __syncthreads();
        if (t < 128) atomicAdd(&statsraw[t], ssum[t]);
        else atomicAdd(&statsraw[t], ssq[t - 128]);
    }
}

// ---------------- dual-output MFMA GEMM (A loaded once) ----------------
__global__ __launch_bounds__(256) void gemm_mfma2(
    const unsigned short* __restrict__ A,
    const unsigned short* __restrict__ Wt0, const unsigned short* __restrict__ Wt1,
    float* __restrict__ V0, float* __restrict__ V1,
    int M, int acc0f, int acc1f, int st0, int st1,
    float* __restrict__ sr0, float* __restrict__ sr1)
{
    __shared__ float ssum0[128], ssq0[128], ssum1[128], ssq1[128];
    int t = threadIdx.x;
    int wave = t >> 6, lane = t & 63;
    int lr = lane & 15, lq = lane >> 4;
    int row0 = blockIdx.x * 64 + wave * 16;

    if (t < 128) { ssum0[t] = 0.f; ssq0[t] = 0.f; ssum1[t] = 0.f; ssq1[t] = 0.f; }
    __syncthreads();

    f32x4 acc0[8], acc1[8];
#pragma unroll
    for (int n = 0; n < 8; n++) { acc0[n] = (f32x4)(0.f); acc1[n] = (f32x4)(0.f); }

    const unsigned short* arow = A + (size_t)(row0 + lr) * 128 + lq * 8;
#pragma unroll
    for (int kt = 0; kt < 4; kt++) {
        bf16x8 af = *(const bf16x8*)(arow + kt * 32);
#pragma unroll
        for (int n = 0; n < 8; n++) {
            size_t bo = (size_t)(n * 16 + lr) * 128 + kt * 32 + lq * 8;
            bf16x8 b0 = *(const bf16x8*)(Wt0 + bo);
            bf16x8 b1 = *(const bf16x8*)(Wt1 + bo);
            acc0[n] = __builtin_amdgcn_mfma_f32_16x16x32_bf16(af, b0, acc0[n], 0, 0, 0);
            acc1[n] = __builtin_amdgcn_mfma_f32_16x16x32_bf16(af, b1, acc1[n], 0, 0, 0);
        }
    }
    gemm_epi(acc0, V0, acc0f, st0, ssum0, ssq0, row0, lr, lq);
    gemm_epi(acc1, V1, acc1f, st1, ssum1, ssq1, row0, lr, lq);
    __syncthreads();
    if (st0) {
        if (t < 128) atomicAdd(&sr0[t], ssum0[t]);
        else atomicAdd(&sr0[t], ssq0[t - 128]);
    }
    if (st1) {
        if (t < 128) atomicAdd(&sr1[t], ssum1[t]);
        else atomicAdd(&sr1[t], ssq1[t - 128]);
    }
}

struct FinArgs { int Ms[10]; };

__global__ void bn_finalize(const float* __restrict__ raw, float* __restrict__ fin, FinArgs fa)
{
    int tt = blockIdx.x;
    int c = threadIdx.x;
    float m = (float)fa.Ms[tt];
    float s = raw[tt * 256 + c], sq = raw[tt * 256 + 128 + c];
    float mu = s / m;
    float var = fmaxf(sq / m - mu * mu, 0.f);
    fin[tt * 256 + c] = mu;
    fin[tt * 256 + 128 + c] = rsqrtf(var + 1e-5f);
}

// ---------------- attention score via MFMA ----------------
__global__ __launch_bounds__(256) void attn_mfma(
    const float* __restrict__ V, const float* __restrict__ st,
    const float* __restrict__ gam, const float* __restrict__ bet,
    const float* __restrict__ pa,
    const unsigned short* __restrict__ W1t, const float* __restrict__ b1,
    const float* __restrict__ w2, float* __restrict__ Sout, int M)
{
    __shared__ float red[4];
    int t = threadIdx.x;
    int wave = t >> 6, lane = t & 63;
    int lr = lane & 15, lq = lane >> 4;
    int row0 = blockIdx.x * 64 + wave * 16;
    float a = *pa;

    f32x4 acc[8];
#pragma unroll
    for (int n = 0; n < 8; n++) acc[n] = (f32x4)(0.f);

    const float* vrow = V + (size_t)(row0 + lr) * D128;
#pragma unroll
    for (int kt = 0; kt < 4; kt++) {
        int k0 = kt * 32 + lq * 8;
        float4 v0 = *(const float4*)(vrow + k0);
        float4 v1 = *(const float4*)(vrow + k0 + 4);
        float4 mu0 = *(const float4*)(st + k0);
        float4 mu1 = *(const float4*)(st + k0 + 4);
        float4 rs0 = *(const float4*)(st + 128 + k0);
        float4 rs1 = *(const float4*)(st + 128 + k0 + 4);
        float4 g0 = *(const float4*)(gam + k0);
        float4 g1 = *(const float4*)(gam + k0 + 4);
        float4 b0 = *(const float4*)(bet + k0);
        float4 b1v = *(const float4*)(bet + k0 + 4);
        float y[8];
        y[0] = g0.x * (v0.x - mu0.x) * rs0.x + b0.x;
        y[1] = g0.y * (v0.y - mu0.y) * rs0.y + b0.y;
        y[2] = g0.z * (v0.z - mu0.z) * rs0.z + b0.z;
        y[3] = g0.w * (v0.w - mu0.w) * rs0.w + b0.w;
        y[4] = g1.x * (v1.x - mu1.x) * rs1.x + b1v.x;
        y[5] = g1.y * (v1.y - mu1.y) * rs1.y + b1v.y;
        y[6] = g1.z * (v1.z - mu1.z) * rs1.z + b1v.z;
        y[7] = g1.w * (v1.w - mu1.w) * rs1.w + b1v.w;
        bf16x8 af;
#pragma unroll
        for (int j = 0; j < 8; j++) {
            float yy = y[j] >= 0.f ? y[j] : a * y[j];
            af[j] = (short)f2bf(yy);
        }
#pragma unroll
        for (int n = 0; n < 8; n++) {
            bf16x8 bfr = *(const bf16x8*)(W1t + (size_t)(n * 16 + lr) * 128 + k0);
            acc[n] = __builtin_amdgcn_mfma_f32_16x16x32_bf16(af, bfr, acc[n], 0, 0, 0);
        }
    }

    float thr = 0.f;
#pragma unroll
    for (int n = 0; n < 8; n++) {
        int col = n * 16 + lr;
        float bc = b1[col], wc = w2[col];
#pragma unroll
        for (int reg = 0; reg < 4; reg++)
            thr += tanhf(acc[n][reg] + bc) * wc;
    }
#pragma unroll
    for (int off = 1; off < 64; off <<= 1)
        thr += __shfl_xor(thr, off);
    if (lane == 0) red[wave] = thr;
    __syncthreads();
    if (t == 0) atomicAdd(Sout, red[0] + red[1] + red[2] + red[3]);
}

// ---------------- final combine ----------------
__global__ void combine(const float* __restrict__ Va, const float* __restrict__ sta,
                        const float* __restrict__ ga, const float* __restrict__ ba,
                        const float* __restrict__ paa,
                        const float* __restrict__ Vb, const float* __restrict__ stb,
                        const float* __restrict__ gb, const float* __restrict__ bb,
                        const float* __restrict__ pab,
                        const float* __restrict__ S, float invM,
                        float* __restrict__ out, int M)
{
    size_t idx = (size_t)blockIdx.x * 256 + threadIdx.x;
    if (idx >= (size_t)M * D128) return;
    int c = (int)(idx & 127);
    float s0 = S[0] * invM, s1 = S[1] * invM;
    float mx = fmaxf(s0, s1);
    float e0 = expf(s0 - mx), e1 = expf(s1 - mx);
    float inv = 1.f / (e0 + e1);
    float b0 = e0 * inv, b1w = e1 * inv;
    float va = Va[idx], vb = Vb[idx];
    float aa = *paa, ab = *pab;
    float ya = ga[c] * (va - sta[c]) * sta[128 + c] + ba[c];
    ya = ya >= 0.f ? ya : aa * ya;
    float yb = gb[c] * (vb - stb[c]) * stb[128 + c] + bb[c];
    yb = yb >= 0.f ? yb : ab * yb;
    out[idx] = b0 * ya + b1w * yb;
}

// ---------------- host orchestration ----------------
extern "C" void kernel_launch(void* const* d_in, const int* in_sizes, int n_in,
                              void* d_out, int out_size, void* d_ws, size_t ws_size,
                              hipStream_t stream)
{
    const float* feats[5] = {
        (const float*)d_in[0], (const float*)d_in[1], (const float*)d_in[2],
        (const float*)d_in[3], (const float*)d_in[4]
    };
    const int featN[5] = {40000, 40000, 80000, 80000, 40000};
    const float* W_blocks = (const float*)d_in[25];
    const float* bn_gamma = (const float*)d_in[27];
    const float* bn_beta  = (const float*)d_in[28];
    const float* prelu_a  = (const float*)d_in[29];
    const float* attn_W1  = (const float*)d_in[30];
    const float* attn_b1  = (const float*)d_in[31];
    const float* attn_w2  = (const float*)d_in[32];
    float* out = (float*)d_out;

    // workspace carve (4-byte slots)
    float* wsf = (float*)d_ws;
    float*    wsv   = wsf;                            // 35,840,000 floats
    unsigned* xbf   = (unsigned*)(wsf + 35840000);    // 5,120,000 uints
    unsigned* aggb  = (unsigned*)(wsf + 40960000);    // 5,120,000 uints
    unsigned short* wtbf = (unsigned short*)(wsf + 46080000); // 262,144 ushorts = 131,072 slots
    int* degs   = (int*)(wsf + 46211072);             // 80,000
    int* cursor = degs + 80000;                       // 80,000
    int* oflow  = cursor + 80000;                     // 8,194 (degs+cursor+oflow: one memset)
    float* statsraw = (float*)(oflow + 8194);         // 2,560
    float* statsfin = statsraw + 2560;                // 2,560
    float* Ssum     = statsfin + 2560;                // 16
    int* tail   = (int*)(Ssum + 16);
    // path A: ebufA = tail .. +5,120,000
    int* ebufA  = tail;
    // path B (fallback, aliases same region): degd, offs, bsums, ebufB
    int* degd   = tail;                               // 80,000
    int* offs   = degd + 80000;                       // 80,001
    int* bsums  = offs + 80001;                       // 64
    int* ebufB  = bsums + 64;                         // 1,280,000

    size_t slots_common = (size_t)(tail - (int*)wsf);
    size_t needed_A = (slots_common + 5120000) * 4;
    size_t needed_B = (slots_common + 80000 + 80001 + 64 + 1280000) * 4;
    if (ws_size < needed_B) return;
    const int capped = (ws_size >= needed_A) ? 1 : 0;

    // tensor table: T0 d0, T1 d1, T2 dis0, T3 dis4, T4 p1, T5 p2, T6 g2, T7 g3, T8 pw3, T9 pw4
    const int Mt[10]  = {40000, 40000, 40000, 40000, 80000, 80000, 80000, 80000, 40000, 40000};
    const int blk[10] = {0, 1, 0, 4, 1, 2, 2, 3, 3, 4};
    const size_t offp[5] = {0, 5120000, 10240000, 20480000, 30720000};
    float* V[10];
    for (int p = 0; p < 5; p++) {
        V[p * 2]     = out + offp[p];
        V[p * 2 + 1] = wsv + offp[p];
    }

    wconv_t<<<16, 256, 0, stream>>>(W_blocks, attn_W1, wtbf);
    hipMemsetAsync(statsraw, 0, 2560 * sizeof(float), stream);
    hipMemsetAsync(Ssum, 0, 16 * sizeof(float), stream);

    struct GJob { int tid; int widx; int accum; int stats; };
    struct RelH { int feat; int srcIn; int ns; int nd; int E; int njob; GJob jobs[2]; };
    const RelH rels[10] = {
        {0,  5, 40000, 40000,  640000, 2, {{0,  0, 0, 1}, {1,  3, 0, 1}}},  // dd
        {0,  7, 40000, 40000,  640000, 1, {{2,  1, 0, 0}, {0,  0, 0, 0}}},  // ddi
        {0, 11, 40000, 80000,  640000, 1, {{4,  4, 0, 0}, {0,  0, 0, 0}}},  // dp
        {1,  9, 40000, 40000,  640000, 2, {{2,  2, 1, 1}, {3, 14, 0, 0}}},  // disdis
        {2, 13, 80000, 80000, 1280000, 2, {{4,  5, 1, 1}, {5,  6, 0, 1}}},  // pp
        {2, 15, 80000, 80000, 1280000, 1, {{6,  7, 0, 0}, {0,  0, 0, 0}}},  // pg
        {3, 17, 80000, 80000, 1280000, 2, {{6,  8, 1, 1}, {7,  9, 0, 1}}},  // gg
        {3, 19, 80000, 40000, 1280000, 1, {{8, 10, 0, 0}, {0,  0, 0, 0}}},  // gpw
        {4, 21, 40000, 40000,  640000, 2, {{8, 11, 1, 1}, {9, 12, 0, 1}}},  // pwpw
        {4, 23, 40000, 40000,  640000, 1, {{3, 13, 1, 1}, {0,  0, 0, 0}}},  // pwdis
    };

    int lastFeat = -1;
    for (int r = 0; r < 10; r++) {
        const RelH& R = rels[r];
        const int* src = (const int*)d_in[R.srcIn];
        const int* dst = (const int*)d_in[R.srcIn + 1];
        if (R.feat != lastFeat) {
            int n_u = featN[R.feat] * 64;
            xconv<<<(n_u / 4 + 255) / 256, 256, 0, stream>>>(feats[R.feat], xbf, n_u);
            lastFeat = R.feat;
        }
        if (capped) {
            // zero degs + cursor + oflow in one shot
            hipMemsetAsync(degs, 0, (size_t)(160000 + 8194) * sizeof(int), stream);
            fused_fill<<<(R.E + 255) / 256, 256, 0, stream>>>(
                src, dst, degs, cursor, ebufA, oflow, R.E);
            gather_bf16<<<R.nd / 4, 256, 0, stream>>>(
                xbf, degs, cursor, offs, ebufA, aggb, R.nd, 1);
            oflow_fix<<<1, 64, 0, stream>>>(xbf, degs, cursor, oflow, aggb);
        } else {
            hipMemsetAsync(degs, 0, (size_t)160000 * sizeof(int), stream);
            hipMemsetAsync(degd, 0, (size_t)R.nd * sizeof(int), stream);
            count_deg<<<(R.E + 255) / 256, 256, 0, stream>>>(src, dst, degs, degd, R.E);
            int nb = (R.nd + 2047) / 2048;
            scan_pass1<<<nb, 256, 0, stream>>>(degd, bsums, R.nd);
            scan_pass2<<<nb, 256, 0, stream>>>(degd, bsums, offs, R.nd);
            fill_buckets<<<(R.E + 255) / 256, 256, 0, stream>>>(src, dst, offs, cursor, ebufB, R.E);
            gather_bf16<<<R.nd / 4, 256, 0, stream>>>(
                xbf, degs, degd, offs, ebufB, aggb, R.nd, 0);
        }
        if (R.njob == 2) {
            const GJob& G0 = R.jobs[0];
            const GJob& G1 = R.jobs[1];
            gemm_mfma2<<<R.nd / 64, 256, 0, stream>>>(
                (const unsigned short*)aggb,
                wtbf + (size_t)G0.widx * 16384, wtbf + (size_t)G1.widx * 16384,
                V[G0.tid], V[G1.tid], R.nd, G0.accum, G1.accum, G0.stats, G1.stats,
                statsraw + (size_t)G0.tid * 256, statsraw + (size_t)G1.tid * 256);
        } else {
            const GJob& G = R.jobs[0];
            gemm_mfma<<<R.nd / 64, 256, 0, stream>>>(
                (const unsigned short*)aggb, wtbf + (size_t)G.widx * 16384,
                V[G.tid], R.nd, G.accum, G.stats, statsraw + (size_t)G.tid * 256);
        }
    }

    FinArgs fa;
    for (int t = 0; t < 10; t++) fa.Ms[t] = Mt[t];
    bn_finalize<<<10, 128, 0, stream>>>(statsraw, statsfin, fa);

    for (int t = 0; t < 10; t++) {
        int p = t / 2, ch = t % 2;
        attn_mfma<<<Mt[t] / 64, 256, 0, stream>>>(
            V[t], statsfin + t * 256,
            bn_gamma + blk[t] * 128, bn_beta + blk[t] * 128, prelu_a + blk[t],
            wtbf + (size_t)15 * 16384, attn_b1, attn_w2, Ssum + p * 2 + ch, Mt[t]);
    }

    for (int p = 0; p < 5; p++) {
        int ta = p * 2, tb = p * 2 + 1;
        combine<<<(Mt[ta] * D128 + 255) / 256, 256, 0, stream>>>(
            V[ta], statsfin + ta * 256, bn_gamma + blk[ta] * 128, bn_beta + blk[ta] * 128, prelu_a + blk[ta],
            V[tb], statsfin + tb * 256, bn_gamma + blk[tb] * 128, bn_beta + blk[tb] * 128, prelu_a + blk[tb],
            Ssum + p * 2, 1.0f / Mt[ta], out + offp[p], Mt[ta]);
    }
}